// Round 10
// baseline (1845.960 us; speedup 1.0000x reference)
//
#include <hip/hip_runtime.h>
#include <hip/hip_bf16.h>

typedef __attribute__((ext_vector_type(8))) short bf16x8;
typedef __attribute__((ext_vector_type(4))) short bf16x4;
typedef __attribute__((ext_vector_type(4))) float f32x4;

#define LB __launch_bounds__(256)

__device__ __forceinline__ unsigned short f2b(float f) {
  __hip_bfloat16 h = __float2bfloat16(f);
  return __builtin_bit_cast(unsigned short, h);
}

// async global->LDS, 16B per lane. LDS dest must be wave-uniform base + lane*16.
#define GLDS(gp, lp)                                                        \
  __builtin_amdgcn_global_load_lds(                                         \
      (const __attribute__((address_space(1))) void*)(gp),                  \
      (__attribute__((address_space(3))) void*)(lp), 16, 0, 0)

// ---------------- embed ----------------
__global__ LB void embed_kernel(const int* __restrict__ idx, const float* __restrict__ tok,
                                const float* __restrict__ pos, float* __restrict__ X) {
  const int m = blockIdx.x;
  const int t = m & 1023;
  const int token = idx[m];
  const int c = threadIdx.x * 4;
  const float4 a = *(const float4*)(tok + (size_t)token * 1024 + c);
  const float4 p = *(const float4*)(pos + (size_t)t * 1024 + c);
  float4 o; o.x = a.x + p.x; o.y = a.y + p.y; o.z = a.z + p.z; o.w = a.w + p.w;
  *(float4*)(X + (size_t)m * 1024 + c) = o;
}

// ---------------- layernorm ----------------
template<bool WF32>
__global__ LB void ln_kernel(const float* __restrict__ X, const float* __restrict__ W,
                             float* __restrict__ Yf, unsigned short* __restrict__ Yb) {
  const int row = blockIdx.x;
  const float* xr = X + (size_t)row * 1024;
  const int c = threadIdx.x * 4;
  const float4 v = *(const float4*)(xr + c);
  float s = v.x + v.y + v.z + v.w;
  float q = v.x*v.x + v.y*v.y + v.z*v.z + v.w*v.w;
  #pragma unroll
  for (int d = 32; d > 0; d >>= 1) { s += __shfl_down(s, d); q += __shfl_down(q, d); }
  __shared__ float ss[4], sq[4];
  const int wid = threadIdx.x >> 6;
  if ((threadIdx.x & 63) == 0) { ss[wid] = s; sq[wid] = q; }
  __syncthreads();
  const float fs = ss[0] + ss[1] + ss[2] + ss[3];
  const float fq = sq[0] + sq[1] + sq[2] + sq[3];
  const float mean = fs * (1.0f / 1024.0f);
  const float var = fq * (1.0f / 1024.0f) - mean * mean;
  const float rstd = rsqrtf(var + 1e-5f);
  const float4 w = *(const float4*)(W + c);
  float4 o;
  o.x = (v.x - mean) * rstd * w.x; o.y = (v.y - mean) * rstd * w.y;
  o.z = (v.z - mean) * rstd * w.z; o.w = (v.w - mean) * rstd * w.w;
  if (WF32) *(float4*)(Yf + (size_t)row * 1024 + c) = o;
  unsigned long long pk = (unsigned long long)f2b(o.x)
      | ((unsigned long long)f2b(o.y) << 16)
      | ((unsigned long long)f2b(o.z) << 32)
      | ((unsigned long long)f2b(o.w) << 48);
  *(unsigned long long*)(Yb + (size_t)row * 1024 + c) = pk;
}

// ---------------- transpose tile body: dst[rowOff+c][r] = bf16(src[r][c]) ----------------
__device__ __forceinline__ void tr_body(const float* __restrict__ src,
                                        unsigned short* __restrict__ dst,
                                        int C, int rowOff, int ldDst, int bx, int by) {
  __shared__ float tile[32][33];
  const int c0 = bx * 32, r0 = by * 32;
  const int tx = threadIdx.x & 31, ty = threadIdx.x >> 5;
  #pragma unroll
  for (int u = 0; u < 4; ++u)
    tile[ty + u * 8][tx] = src[(size_t)(r0 + ty + u * 8) * C + c0 + tx];
  __syncthreads();
  const int ci = threadIdx.x >> 4;
  const int rp = threadIdx.x & 15;
  #pragma unroll
  for (int u = 0; u < 2; ++u) {
    const int c = ci + u * 16;
    unsigned int pk = (unsigned int)f2b(tile[rp * 2][c])
                    | ((unsigned int)f2b(tile[rp * 2 + 1][c]) << 16);
    *(unsigned int*)&dst[(size_t)(rowOff + c0 + c) * ldDst + r0 + rp * 2] = pk;
  }
}

// lm_head transpose (standalone)
__global__ LB void transpose_w(const float* __restrict__ src, unsigned short* __restrict__ dst,
                               int C, int rowOff, int ldDst) {
  tr_body(src, dst, C, rowOff, ldDst, blockIdx.x, blockIdx.y);
}

// batched q/out/k/v transpose: 2560 flat blocks per layer; blockIdx.y = layer
__global__ LB void transpose_qkvo(const float* __restrict__ qp, const float* __restrict__ op,
                                  const float* __restrict__ kvp, unsigned short* __restrict__ dst) {
  const int l = blockIdx.y;
  qp  += (size_t)l * 1024 * 1024;
  op  += (size_t)l * 1024 * 1024;
  kvp += (size_t)l * 2 * 1024 * 256;
  dst += (size_t)l * 2560 * 1024;
  int id = blockIdx.x;
  const float* src; int C, rowOff, bx, by;
  if (id < 2048) {
    src = (id < 1024) ? qp : op;
    rowOff = (id < 1024) ? 0 : 1536;
    id &= 1023; C = 1024; bx = id & 31; by = id >> 5;
  } else {
    id -= 2048;
    src = (id < 256) ? kvp : (kvp + 1024 * 256);
    rowOff = (id < 256) ? 1024 : 1280;
    id &= 255; C = 256; bx = id & 7; by = id >> 3;
  }
  tr_body(src, dst, C, rowOff, 1024, bx, by);
}

// batched fc1/fc2 transpose: 8192 flat blocks per layer; blockIdx.y = layer
__global__ LB void transpose_fc(const float* __restrict__ f1, const float* __restrict__ f2,
                                unsigned short* __restrict__ F1T, unsigned short* __restrict__ F2T) {
  const int l = blockIdx.y;
  f1  += (size_t)l * 1024 * 4096;
  f2  += (size_t)l * 4096 * 1024;
  F1T += (size_t)l * 4096 * 1024;
  F2T += (size_t)l * 4096 * 1024;
  int id = blockIdx.x;
  if (id < 4096) {
    tr_body(f1, F1T, 4096, 0, 1024, id & 127, id >> 7);
  } else {
    id -= 4096;
    tr_body(f2, F2T, 1024, 0, 4096, id & 31, id >> 5);
  }
}

// ---------------- v transpose: vT[b][n*64+d][t] ----------------
__global__ LB void transpose_v(const unsigned short* __restrict__ src, unsigned short* __restrict__ dst) {
  __shared__ unsigned short tile[32][33];
  const int b = blockIdx.z;
  const int c0 = blockIdx.x * 32, t0 = blockIdx.y * 32;
  const int tx = threadIdx.x & 31, ty = threadIdx.x >> 5;
  #pragma unroll
  for (int u = 0; u < 4; ++u)
    tile[ty + u * 8][tx] = src[(size_t)(b * 1024 + t0 + ty + u * 8) * 1536 + 1280 + c0 + tx];
  __syncthreads();
  #pragma unroll
  for (int u = 0; u < 4; ++u)
    dst[((size_t)b * 256 + c0 + ty + u * 8) * 1024 + t0 + tx] = tile[tx][ty + u * 8];
}

// ---------------- fused flash attention (staged, barriered) ----------------
__global__ LB void attn_fused(const unsigned short* __restrict__ qkvb,
                              const unsigned short* __restrict__ vT,
                              unsigned short* __restrict__ ob) {
  const int qt = blockIdx.x, bh = blockIdx.y;
  const int b = bh >> 4, hh = bh & 15, n = hh & 3;
  const int tid = threadIdx.x, lane = tid & 63, w = tid >> 6;
  const int g = lane >> 4, c = lane & 15;
  const int q0w = qt * 128 + w * 32;
  const int kdiag = q0w >> 6;

  __shared__ unsigned short lsK[64 * 64];
  __shared__ unsigned short lsV[64 * 64];
  __shared__ unsigned short lsP[4][32 * 64];
  unsigned short* Pw = lsP[w];

  bf16x8 qf[2][2];
  {
    const unsigned short* Qb = qkvb + (size_t)(b * 1024 + q0w) * 1536 + hh * 64;
    #pragma unroll
    for (int nj = 0; nj < 2; ++nj)
      #pragma unroll
      for (int ks = 0; ks < 2; ++ks)
        qf[nj][ks] = *(const bf16x8*)(Qb + (size_t)(nj * 16 + c) * 1536 + ks * 32 + g * 8);
  }

  f32x4 accO[2][4] = {};
  float mrow[2] = {-1e30f, -1e30f};
  float lrow[2] = {0.0f, 0.0f};

  const int srow = tid >> 3;
  const int scol = ((tid & 7) ^ (srow & 7)) << 3;
  const unsigned short* gK = qkvb + (size_t)(b * 1024 + srow) * 1536 + 1024 + n * 64 + scol;
  const unsigned short* gV = vT + (size_t)((b * 4 + n) * 64 + srow) * 1024 + scol;
  unsigned short* lK = lsK + tid * 8;
  unsigned short* lV = lsV + tid * 8;

  const int ktmax = 2 * qt + 1;
  for (int kt = 0; kt <= ktmax; ++kt) {
    if (kt) __syncthreads();
    GLDS(gK + (size_t)kt * 64 * 1536, lK);
    GLDS(gK + (size_t)kt * 64 * 1536 + (size_t)32 * 1536, lK + 2048);
    GLDS(gV + (size_t)kt * 64, lV);
    GLDS(gV + (size_t)kt * 64 + (size_t)32 * 1024, lV + 2048);
    __syncthreads();
    if (kt > kdiag) continue;

    const bool dg = (kt == kdiag);
    const int kb = kt * 64;

    f32x4 st[4][2] = {};
    #pragma unroll
    for (int ks = 0; ks < 2; ++ks) {
      const int col = (((ks * 4 + g) ^ (lane & 7)) << 3);
      bf16x8 kf[4];
      #pragma unroll
      for (int mi = 0; mi < 4; ++mi)
        kf[mi] = *(const bf16x8*)&lsK[(mi * 16 + c) * 64 + col];
      #pragma unroll
      for (int mi = 0; mi < 4; ++mi)
        #pragma unroll
        for (int nj = 0; nj < 2; ++nj)
          st[mi][nj] = __builtin_amdgcn_mfma_f32_16x16x32_bf16(kf[mi], qf[nj][ks], st[mi][nj], 0, 0, 0);
    }

    float alv[2];
    #pragma unroll
    for (int nj = 0; nj < 2; ++nj) {
      const int qrow = q0w + nj * 16 + c;
      float mx = mrow[nj];
      #pragma unroll
      for (int mi = 0; mi < 4; ++mi)
        #pragma unroll
        for (int j = 0; j < 4; ++j) {
          float v = st[mi][nj][j] * 0.125f;
          if (dg && (kb + mi * 16 + g * 4 + j) > qrow) v = -1e30f;
          st[mi][nj][j] = v;
          mx = fmaxf(mx, v);
        }
      mx = fmaxf(mx, __shfl_xor(mx, 16));
      mx = fmaxf(mx, __shfl_xor(mx, 32));
      const float al = __expf(mrow[nj] - mx);
      float sum = 0.0f;
      #pragma unroll
      for (int mi = 0; mi < 4; ++mi) {
        bf16x4 pk;
        #pragma unroll
        for (int j = 0; j < 4; ++j) {
          const float e = __expf(st[mi][nj][j] - mx);
          sum += e;
          pk[j] = (short)f2b(e);
        }
        *(bf16x4*)&Pw[(nj * 16 + c) * 64 + ((mi * 16 + g * 4) ^ ((c & 7) << 3))] = pk;
      }
      sum += __shfl_xor(sum, 16);
      sum += __shfl_xor(sum, 32);
      lrow[nj] = lrow[nj] * al + sum;
      mrow[nj] = mx;
      alv[nj] = al;
    }

    #pragma unroll
    for (int mi = 0; mi < 2; ++mi) {
      float aj[4];
      #pragma unroll
      for (int j = 0; j < 4; ++j) aj[j] = __shfl(alv[mi], g * 4 + j);
      #pragma unroll
      for (int dj = 0; dj < 4; ++dj)
        #pragma unroll
        for (int j = 0; j < 4; ++j) accO[mi][dj][j] *= aj[j];
    }

    #pragma unroll
    for (int ks = 0; ks < 2; ++ks) {
      const int col = (((ks * 4 + g) ^ (lane & 7)) << 3);
      bf16x8 pa[2], vf[4];
      #pragma unroll
      for (int mi = 0; mi < 2; ++mi)
        pa[mi] = *(const bf16x8*)&Pw[(mi * 16 + c) * 64 + col];
      #pragma unroll
      for (int dj = 0; dj < 4; ++dj)
        vf[dj] = *(const bf16x8*)&lsV[(dj * 16 + c) * 64 + col];
      #pragma unroll
      for (int mi = 0; mi < 2; ++mi)
        #pragma unroll
        for (int dj = 0; dj < 4; ++dj)
          accO[mi][dj] = __builtin_amdgcn_mfma_f32_16x16x32_bf16(pa[mi], vf[dj], accO[mi][dj], 0, 0, 0);
    }
  }

  float linv[2] = {1.0f / lrow[0], 1.0f / lrow[1]};
  unsigned short* obase = ob + (size_t)(b * 1024 + q0w) * 1024 + hh * 64;
  #pragma unroll
  for (int mi = 0; mi < 2; ++mi) {
    float lj[4];
    #pragma unroll
    for (int j = 0; j < 4; ++j) lj[j] = __shfl(linv[mi], g * 4 + j);
    #pragma unroll
    for (int dj = 0; dj < 4; ++dj)
      #pragma unroll
      for (int j = 0; j < 4; ++j)
        obase[(size_t)(mi * 16 + g * 4 + j) * 1024 + dj * 16 + c] = f2b(accO[mi][dj][j] * lj[j]);
  }
}

// ---------------- NT GEMM: C = A[M,K]*Bt[N,K]^T, bf16 in, f32 acc ----------------
template<int BM, int BN, bool BF16OUT, bool RELU, bool RESID>
__global__ LB void gemm_nt(const unsigned short* __restrict__ A, const unsigned short* __restrict__ Bt,
                           void* __restrict__ Cv, const float* __restrict__ Res,
                           int K, int lda, int ldb, int ldc) {
  constexpr int BK = 64;
  constexpr int WM = BM / 2, WN = BN / 2;
  constexpr int FM = WM / 16, FN = WN / 16;
  constexpr int PA = BM / 32, PB = BN / 32;
  int f = blockIdx.x + gridDim.x * blockIdx.y;
  const int nwg = gridDim.x * gridDim.y;
  if ((nwg & 7) == 0) f = (f & 7) * (nwg >> 3) + (f >> 3);
  const int bx = f % gridDim.x, by = f / gridDim.x;

  const int tid = threadIdx.x;
  const int lane = tid & 63, wid = tid >> 6;
  const int wr = wid >> 1, wc = wid & 1;
  const int m0 = bx * BM, n0 = by * BN;

  __shared__ unsigned short lsA[BM * BK];
  __shared__ unsigned short lsB[BN * BK];

  f32x4 acc[FM][FN] = {};

  const int srow = tid >> 3;
  const int scol = ((tid & 7) ^ (srow & 7)) << 3;
  const unsigned short* gA = A + (size_t)(m0 + srow) * lda + scol;
  const unsigned short* gB = Bt + (size_t)(n0 + srow) * ldb + scol;
  unsigned short* lA = lsA + tid * 8;
  unsigned short* lB = lsB + tid * 8;

  const int fr = lane & 15;
  const int j7 = lane & 7;
  const int g4 = lane >> 4;

  for (int k0 = 0; k0 < K; k0 += BK) {
    if (k0) __syncthreads();
    #pragma unroll
    for (int p = 0; p < PA; ++p)
      GLDS(gA + (size_t)(p * 32) * lda + k0, lA + p * 2048);
    #pragma unroll
    for (int p = 0; p < PB; ++p)
      GLDS(gB + (size_t)(p * 32) * ldb + k0, lB + p * 2048);
    __syncthreads();

    #pragma unroll
    for (int ks = 0; ks < 2; ++ks) {
      const int col = (((ks * 4 + g4) ^ j7) << 3);
      bf16x8 af[FM], bfv[FN];
      #pragma unroll
      for (int mi = 0; mi < FM; ++mi)
        af[mi] = *(const bf16x8*)&lsA[(wr * WM + mi * 16 + fr) * BK + col];
      #pragma unroll
      for (int nj = 0; nj < FN; ++nj)
        bfv[nj] = *(const bf16x8*)&lsB[(wc * WN + nj * 16 + fr) * BK + col];
      #pragma unroll
      for (int mi = 0; mi < FM; ++mi)
        #pragma unroll
        for (int nj = 0; nj < FN; ++nj)
          acc[mi][nj] = __builtin_amdgcn_mfma_f32_16x16x32_bf16(af[mi], bfv[nj], acc[mi][nj], 0, 0, 0);
    }
  }

  const int r0 = (lane >> 4) * 4, c0 = lane & 15;
  #pragma unroll
  for (int mi = 0; mi < FM; ++mi) {
    #pragma unroll
    for (int nj = 0; nj < FN; ++nj) {
      const int c = n0 + wc * WN + nj * 16 + c0;
      #pragma unroll
      for (int j = 0; j < 4; ++j) {
        const int r = m0 + wr * WM + mi * 16 + r0 + j;
        float v = acc[mi][nj][j];
        if (RELU) v = fmaxf(v, 0.0f);
        if (RESID) v += Res[(size_t)r * ldc + c];
        const size_t o = (size_t)r * ldc + c;
        if (BF16OUT) ((unsigned short*)Cv)[o] = f2b(v);
        else ((float*)Cv)[o] = v;
      }
    }
  }
}

extern "C" void kernel_launch(void* const* d_in, const int* in_sizes, int n_in,
                              void* d_out, int out_size, void* d_ws, size_t ws_size,
                              hipStream_t stream) {
  (void)in_sizes; (void)n_in; (void)out_size;
  const int*   idx      = (const int*)d_in[0];
  const float* tok_emb  = (const float*)d_in[1];
  const float* pos_emb  = (const float*)d_in[2];
  const float* q_proj   = (const float*)d_in[3];
  const float* kv_proj  = (const float*)d_in[4];
  const float* out_proj = (const float*)d_in[5];
  const float* fc_in    = (const float*)d_in[6];
  const float* fc_out   = (const float*)d_in[7];
  const float* scale    = (const float*)d_in[8];
  const float* out_scl  = (const float*)d_in[9];
  const float* lm_head  = (const float*)d_in[10];
  float* out = (float*)d_out;

  char* ws = (char*)d_ws;
  size_t off = 0;
  auto alloc = [&](size_t bytes) -> void* {
    void* p = ws + off;
    off += (bytes + 255) & ~(size_t)255;
    return p;
  };
  // common buffers
  float*  xbuf  = (float*)alloc((size_t)2048 * 1024 * 4);
  float*  hbuf  = (float*)alloc((size_t)2048 * 1024 * 4);
  float*  h2buf = (float*)alloc((size_t)2048 * 1024 * 4);
  unsigned short* actb  = (unsigned short*)alloc((size_t)2048 * 1024 * 2);
  unsigned short* qkvb  = (unsigned short*)alloc((size_t)2048 * 1536 * 2);
  unsigned short* vT    = (unsigned short*)alloc((size_t)2 * 256 * 1024 * 2);
  unsigned short* LmT   = (unsigned short*)alloc((size_t)32000 * 1024 * 2);
  unsigned short* ob    = (unsigned short*)alloc((size_t)2048 * 1024 * 2);
  unsigned short* m1    = (unsigned short*)alloc((size_t)2048 * 4096 * 2);
  const size_t off_common = off;

  // try all-layers weight area (big path); fall back to per-layer if ws too small
  unsigned short* WQ = (unsigned short*)alloc((size_t)8 * 2560 * 1024 * 2);
  unsigned short* F1 = (unsigned short*)alloc((size_t)8 * 4096 * 1024 * 2);
  unsigned short* F2 = (unsigned short*)alloc((size_t)8 * 4096 * 1024 * 2);
  bool big = (off <= ws_size);
  if (!big) {
    off = off_common;
    WQ = (unsigned short*)alloc((size_t)2560 * 1024 * 2);
    F1 = (unsigned short*)alloc((size_t)4096 * 1024 * 2);
    F2 = (unsigned short*)alloc((size_t)4096 * 1024 * 2);
    if (off > ws_size) return;
  }

  const dim3 thr(256);

  embed_kernel<<<dim3(2048), thr, 0, stream>>>(idx, tok_emb, pos_emb, xbuf);

  if (big) {  // all 8 layers' weights transposed in 2 launches
    transpose_qkvo<<<dim3(2560, 8), thr, 0, stream>>>(q_proj, out_proj, kv_proj, WQ);
    transpose_fc<<<dim3(8192, 8), thr, 0, stream>>>(fc_in, fc_out, F1, F2);
  }

  for (int l = 0; l < 8; ++l) {
    unsigned short* WqkvT = WQ + (big ? (size_t)l * 2560 * 1024 : 0);
    unsigned short* WoT   = WqkvT + (size_t)1536 * 1024;
    unsigned short* F1T   = F1 + (big ? (size_t)l * 4096 * 1024 : 0);
    unsigned short* F2T   = F2 + (big ? (size_t)l * 4096 * 1024 : 0);
    if (!big) {
      transpose_qkvo<<<dim3(2560, 1), thr, 0, stream>>>(
          q_proj + (size_t)l * 1024 * 1024, out_proj + (size_t)l * 1024 * 1024,
          kv_proj + (size_t)l * 2 * 1024 * 256, WqkvT);
      transpose_fc<<<dim3(8192, 1), thr, 0, stream>>>(
          fc_in + (size_t)l * 1024 * 4096, fc_out + (size_t)l * 4096 * 1024, F1T, F2T);
    }

    const float* w1 = scale + (size_t)l * 2048;
    const float* w2 = w1 + 1024;

    ln_kernel<true><<<dim3(2048), thr, 0, stream>>>(xbuf, w1, hbuf, actb);
    gemm_nt<128, 64, true, false, false><<<dim3(16, 24), thr, 0, stream>>>(
        actb, WqkvT, qkvb, nullptr, 1024, 1024, 1024, 1536);
    transpose_v<<<dim3(8, 32, 2), thr, 0, stream>>>(qkvb, vT);
    attn_fused<<<dim3(8, 32), thr, 0, stream>>>(qkvb, vT, ob);
    gemm_nt<128, 64, false, false, true><<<dim3(16, 16), thr, 0, stream>>>(
        ob, WoT, xbuf, hbuf, 1024, 1024, 1024, 1024);
    ln_kernel<true><<<dim3(2048), thr, 0, stream>>>(xbuf, w2, h2buf, actb);
    gemm_nt<128, 128, true, true, false><<<dim3(16, 32), thr, 0, stream>>>(
        actb, F1T, m1, nullptr, 1024, 1024, 1024, 4096);
    gemm_nt<128, 64, false, false, true><<<dim3(16, 16), thr, 0, stream>>>(
        m1, F2T, xbuf, h2buf, 4096, 4096, 4096, 1024);
  }

  transpose_w<<<dim3(1000, 32), thr, 0, stream>>>(lm_head, LmT, 32000, 0, 1024);
  ln_kernel<false><<<dim3(2048), thr, 0, stream>>>(xbuf, out_scl, nullptr, actb);
  gemm_nt<128, 128, false, false, false><<<dim3(16, 250), thr, 0, stream>>>(
      actb, LmT, out, nullptr, 1024, 1024, 1024, 32000);
}

// Round 11
// 1702.317 us; speedup vs baseline: 1.0844x; 1.0844x over previous
//
#include <hip/hip_runtime.h>
#include <hip/hip_bf16.h>

typedef __attribute__((ext_vector_type(8))) short bf16x8;
typedef __attribute__((ext_vector_type(4))) short bf16x4;
typedef __attribute__((ext_vector_type(4))) float f32x4;

#define LB __launch_bounds__(256)

__device__ __forceinline__ unsigned short f2b(float f) {
  __hip_bfloat16 h = __float2bfloat16(f);
  return __builtin_bit_cast(unsigned short, h);
}

// async global->LDS, 16B per lane. LDS dest must be wave-uniform base + lane*16.
#define GLDS(gp, lp)                                                        \
  __builtin_amdgcn_global_load_lds(                                         \
      (const __attribute__((address_space(1))) void*)(gp),                  \
      (__attribute__((address_space(3))) void*)(lp), 16, 0, 0)

// ---------------- embed ----------------
__global__ LB void embed_kernel(const int* __restrict__ idx, const float* __restrict__ tok,
                                const float* __restrict__ pos, float* __restrict__ X) {
  const int m = blockIdx.x;
  const int t = m & 1023;
  const int token = idx[m];
  const int c = threadIdx.x * 4;
  const float4 a = *(const float4*)(tok + (size_t)token * 1024 + c);
  const float4 p = *(const float4*)(pos + (size_t)t * 1024 + c);
  float4 o; o.x = a.x + p.x; o.y = a.y + p.y; o.z = a.z + p.z; o.w = a.w + p.w;
  *(float4*)(X + (size_t)m * 1024 + c) = o;
}

// ---------------- layernorm ----------------
template<bool WF32>
__global__ LB void ln_kernel(const float* __restrict__ X, const float* __restrict__ W,
                             float* __restrict__ Yf, unsigned short* __restrict__ Yb) {
  const int row = blockIdx.x;
  const float* xr = X + (size_t)row * 1024;
  const int c = threadIdx.x * 4;
  const float4 v = *(const float4*)(xr + c);
  float s = v.x + v.y + v.z + v.w;
  float q = v.x*v.x + v.y*v.y + v.z*v.z + v.w*v.w;
  #pragma unroll
  for (int d = 32; d > 0; d >>= 1) { s += __shfl_down(s, d); q += __shfl_down(q, d); }
  __shared__ float ss[4], sq[4];
  const int wid = threadIdx.x >> 6;
  if ((threadIdx.x & 63) == 0) { ss[wid] = s; sq[wid] = q; }
  __syncthreads();
  const float fs = ss[0] + ss[1] + ss[2] + ss[3];
  const float fq = sq[0] + sq[1] + sq[2] + sq[3];
  const float mean = fs * (1.0f / 1024.0f);
  const float var = fq * (1.0f / 1024.0f) - mean * mean;
  const float rstd = rsqrtf(var + 1e-5f);
  const float4 w = *(const float4*)(W + c);
  float4 o;
  o.x = (v.x - mean) * rstd * w.x; o.y = (v.y - mean) * rstd * w.y;
  o.z = (v.z - mean) * rstd * w.z; o.w = (v.w - mean) * rstd * w.w;
  if (WF32) *(float4*)(Yf + (size_t)row * 1024 + c) = o;
  unsigned long long pk = (unsigned long long)f2b(o.x)
      | ((unsigned long long)f2b(o.y) << 16)
      | ((unsigned long long)f2b(o.z) << 32)
      | ((unsigned long long)f2b(o.w) << 48);
  *(unsigned long long*)(Yb + (size_t)row * 1024 + c) = pk;
}

// ---------------- transpose tile body: dst[rowOff+c][r] = bf16(src[r][c]) ----------------
__device__ __forceinline__ void tr_body(const float* __restrict__ src,
                                        unsigned short* __restrict__ dst,
                                        int C, int rowOff, int ldDst, int bx, int by) {
  __shared__ float tile[32][33];
  const int c0 = bx * 32, r0 = by * 32;
  const int tx = threadIdx.x & 31, ty = threadIdx.x >> 5;
  #pragma unroll
  for (int u = 0; u < 4; ++u)
    tile[ty + u * 8][tx] = src[(size_t)(r0 + ty + u * 8) * C + c0 + tx];
  __syncthreads();
  const int ci = threadIdx.x >> 4;
  const int rp = threadIdx.x & 15;
  #pragma unroll
  for (int u = 0; u < 2; ++u) {
    const int c = ci + u * 16;
    unsigned int pk = (unsigned int)f2b(tile[rp * 2][c])
                    | ((unsigned int)f2b(tile[rp * 2 + 1][c]) << 16);
    *(unsigned int*)&dst[(size_t)(rowOff + c0 + c) * ldDst + r0 + rp * 2] = pk;
  }
}

// lm_head transpose (standalone)
__global__ LB void transpose_w(const float* __restrict__ src, unsigned short* __restrict__ dst,
                               int C, int rowOff, int ldDst) {
  tr_body(src, dst, C, rowOff, ldDst, blockIdx.x, blockIdx.y);
}

// batched q/out/k/v transpose: 2560 flat blocks
__global__ LB void transpose_qkvo(const float* __restrict__ qp, const float* __restrict__ op,
                                  const float* __restrict__ kvp, unsigned short* __restrict__ dst) {
  int id = blockIdx.x;
  const float* src; int C, rowOff, bx, by;
  if (id < 2048) {
    src = (id < 1024) ? qp : op;
    rowOff = (id < 1024) ? 0 : 1536;
    id &= 1023; C = 1024; bx = id & 31; by = id >> 5;
  } else {
    id -= 2048;
    src = (id < 256) ? kvp : (kvp + 1024 * 256);
    rowOff = (id < 256) ? 1024 : 1280;
    id &= 255; C = 256; bx = id & 7; by = id >> 3;
  }
  tr_body(src, dst, C, rowOff, 1024, bx, by);
}

// batched fc1/fc2 transpose: 8192 flat blocks
__global__ LB void transpose_fc(const float* __restrict__ f1, const float* __restrict__ f2,
                                unsigned short* __restrict__ F1T, unsigned short* __restrict__ F2T) {
  int id = blockIdx.x;
  if (id < 4096) {
    tr_body(f1, F1T, 4096, 0, 1024, id & 127, id >> 7);
  } else {
    id -= 4096;
    tr_body(f2, F2T, 1024, 0, 4096, id & 31, id >> 5);
  }
}

// ---------------- v transpose: vT[b][n*64+d][t] ----------------
__global__ LB void transpose_v(const unsigned short* __restrict__ src, unsigned short* __restrict__ dst) {
  __shared__ unsigned short tile[32][33];
  const int b = blockIdx.z;
  const int c0 = blockIdx.x * 32, t0 = blockIdx.y * 32;
  const int tx = threadIdx.x & 31, ty = threadIdx.x >> 5;
  #pragma unroll
  for (int u = 0; u < 4; ++u)
    tile[ty + u * 8][tx] = src[(size_t)(b * 1024 + t0 + ty + u * 8) * 1536 + 1280 + c0 + tx];
  __syncthreads();
  #pragma unroll
  for (int u = 0; u < 4; ++u)
    dst[((size_t)b * 256 + c0 + ty + u * 8) * 1024 + t0 + tx] = tile[tx][ty + u * 8];
}

// ---------------- fused flash attention (staged, barriered) ----------------
__global__ LB void attn_fused(const unsigned short* __restrict__ qkvb,
                              const unsigned short* __restrict__ vT,
                              unsigned short* __restrict__ ob) {
  const int qt = blockIdx.x, bh = blockIdx.y;
  const int b = bh >> 4, hh = bh & 15, n = hh & 3;
  const int tid = threadIdx.x, lane = tid & 63, w = tid >> 6;
  const int g = lane >> 4, c = lane & 15;
  const int q0w = qt * 128 + w * 32;
  const int kdiag = q0w >> 6;

  __shared__ unsigned short lsK[64 * 64];
  __shared__ unsigned short lsV[64 * 64];
  __shared__ unsigned short lsP[4][32 * 64];
  unsigned short* Pw = lsP[w];

  bf16x8 qf[2][2];
  {
    const unsigned short* Qb = qkvb + (size_t)(b * 1024 + q0w) * 1536 + hh * 64;
    #pragma unroll
    for (int nj = 0; nj < 2; ++nj)
      #pragma unroll
      for (int ks = 0; ks < 2; ++ks)
        qf[nj][ks] = *(const bf16x8*)(Qb + (size_t)(nj * 16 + c) * 1536 + ks * 32 + g * 8);
  }

  f32x4 accO[2][4] = {};
  float mrow[2] = {-1e30f, -1e30f};
  float lrow[2] = {0.0f, 0.0f};

  const int srow = tid >> 3;
  const int scol = ((tid & 7) ^ (srow & 7)) << 3;
  const unsigned short* gK = qkvb + (size_t)(b * 1024 + srow) * 1536 + 1024 + n * 64 + scol;
  const unsigned short* gV = vT + (size_t)((b * 4 + n) * 64 + srow) * 1024 + scol;
  unsigned short* lK = lsK + tid * 8;
  unsigned short* lV = lsV + tid * 8;

  const int ktmax = 2 * qt + 1;
  for (int kt = 0; kt <= ktmax; ++kt) {
    if (kt) __syncthreads();
    GLDS(gK + (size_t)kt * 64 * 1536, lK);
    GLDS(gK + (size_t)kt * 64 * 1536 + (size_t)32 * 1536, lK + 2048);
    GLDS(gV + (size_t)kt * 64, lV);
    GLDS(gV + (size_t)kt * 64 + (size_t)32 * 1024, lV + 2048);
    __syncthreads();
    if (kt > kdiag) continue;

    const bool dg = (kt == kdiag);
    const int kb = kt * 64;

    f32x4 st[4][2] = {};
    #pragma unroll
    for (int ks = 0; ks < 2; ++ks) {
      const int col = (((ks * 4 + g) ^ (lane & 7)) << 3);
      bf16x8 kf[4];
      #pragma unroll
      for (int mi = 0; mi < 4; ++mi)
        kf[mi] = *(const bf16x8*)&lsK[(mi * 16 + c) * 64 + col];
      #pragma unroll
      for (int mi = 0; mi < 4; ++mi)
        #pragma unroll
        for (int nj = 0; nj < 2; ++nj)
          st[mi][nj] = __builtin_amdgcn_mfma_f32_16x16x32_bf16(kf[mi], qf[nj][ks], st[mi][nj], 0, 0, 0);
    }

    float alv[2];
    #pragma unroll
    for (int nj = 0; nj < 2; ++nj) {
      const int qrow = q0w + nj * 16 + c;
      float mx = mrow[nj];
      #pragma unroll
      for (int mi = 0; mi < 4; ++mi)
        #pragma unroll
        for (int j = 0; j < 4; ++j) {
          float v = st[mi][nj][j] * 0.125f;
          if (dg && (kb + mi * 16 + g * 4 + j) > qrow) v = -1e30f;
          st[mi][nj][j] = v;
          mx = fmaxf(mx, v);
        }
      mx = fmaxf(mx, __shfl_xor(mx, 16));
      mx = fmaxf(mx, __shfl_xor(mx, 32));
      const float al = __expf(mrow[nj] - mx);
      float sum = 0.0f;
      #pragma unroll
      for (int mi = 0; mi < 4; ++mi) {
        bf16x4 pk;
        #pragma unroll
        for (int j = 0; j < 4; ++j) {
          const float e = __expf(st[mi][nj][j] - mx);
          sum += e;
          pk[j] = (short)f2b(e);
        }
        *(bf16x4*)&Pw[(nj * 16 + c) * 64 + ((mi * 16 + g * 4) ^ ((c & 7) << 3))] = pk;
      }
      sum += __shfl_xor(sum, 16);
      sum += __shfl_xor(sum, 32);
      lrow[nj] = lrow[nj] * al + sum;
      mrow[nj] = mx;
      alv[nj] = al;
    }

    #pragma unroll
    for (int mi = 0; mi < 2; ++mi) {
      float aj[4];
      #pragma unroll
      for (int j = 0; j < 4; ++j) aj[j] = __shfl(alv[mi], g * 4 + j);
      #pragma unroll
      for (int dj = 0; dj < 4; ++dj)
        #pragma unroll
        for (int j = 0; j < 4; ++j) accO[mi][dj][j] *= aj[j];
    }

    #pragma unroll
    for (int ks = 0; ks < 2; ++ks) {
      const int col = (((ks * 4 + g) ^ (lane & 7)) << 3);
      bf16x8 pa[2], vf[4];
      #pragma unroll
      for (int mi = 0; mi < 2; ++mi)
        pa[mi] = *(const bf16x8*)&Pw[(mi * 16 + c) * 64 + col];
      #pragma unroll
      for (int dj = 0; dj < 4; ++dj)
        vf[dj] = *(const bf16x8*)&lsV[(dj * 16 + c) * 64 + col];
      #pragma unroll
      for (int mi = 0; mi < 2; ++mi)
        #pragma unroll
        for (int dj = 0; dj < 4; ++dj)
          accO[mi][dj] = __builtin_amdgcn_mfma_f32_16x16x32_bf16(pa[mi], vf[dj], accO[mi][dj], 0, 0, 0);
    }
  }

  float linv[2] = {1.0f / lrow[0], 1.0f / lrow[1]};
  unsigned short* obase = ob + (size_t)(b * 1024 + q0w) * 1024 + hh * 64;
  #pragma unroll
  for (int mi = 0; mi < 2; ++mi) {
    float lj[4];
    #pragma unroll
    for (int j = 0; j < 4; ++j) lj[j] = __shfl(linv[mi], g * 4 + j);
    #pragma unroll
    for (int dj = 0; dj < 4; ++dj)
      #pragma unroll
      for (int j = 0; j < 4; ++j)
        obase[(size_t)(mi * 16 + g * 4 + j) * 1024 + dj * 16 + c] = f2b(accO[mi][dj][j] * lj[j]);
  }
}

// ---------------- NT GEMM: C = A[M,K]*Bt[N,K]^T, bf16 in, f32 acc ----------------
// QUAD=false: chunk XCD swizzle (M fastest). QUAD=true (logits): per-XCD quad
// traversal — XCD x owns 32 N-groups; 8 quads of 4 groups; all 16 M-blocks per
// quad swept before next quad. Working set 4 A-slices + 4 B-panels = 2MB < L2.
// Grid must be (16, 256); by >= nby blocks exit.
template<int BM, int BN, bool BF16OUT, bool RELU, bool RESID, bool QUAD = false>
__global__ LB void gemm_nt(const unsigned short* __restrict__ A, const unsigned short* __restrict__ Bt,
                           void* __restrict__ Cv, const float* __restrict__ Res,
                           int K, int lda, int ldb, int ldc, int nby) {
  constexpr int BK = 64;
  constexpr int WM = BM / 2, WN = BN / 2;
  constexpr int FM = WM / 16, FN = WN / 16;
  constexpr int PA = BM / 32, PB = BN / 32;
  int bx, by;
  if (QUAD) {
    const int orig = blockIdx.x + (int)(gridDim.x * blockIdx.y);
    const int x = orig & 7, s = orig >> 3;        // XCD, slot in [0,512)
    bx = s & 15;                                  // M sweep within quad
    by = x * 32 + ((s >> 6) << 2) + ((s & 63) >> 4);
    if (by >= nby) return;                        // padded tail
  } else {
    int f = blockIdx.x + gridDim.x * blockIdx.y;
    const int nwg = gridDim.x * gridDim.y;
    if ((nwg & 7) == 0) f = (f & 7) * (nwg >> 3) + (f >> 3);
    bx = f % gridDim.x; by = f / gridDim.x;
  }

  const int tid = threadIdx.x;
  const int lane = tid & 63, wid = tid >> 6;
  const int wr = wid >> 1, wc = wid & 1;
  const int m0 = bx * BM, n0 = by * BN;

  __shared__ unsigned short lsA[BM * BK];
  __shared__ unsigned short lsB[BN * BK];

  f32x4 acc[FM][FN] = {};

  const int srow = tid >> 3;
  const int scol = ((tid & 7) ^ (srow & 7)) << 3;
  const unsigned short* gA = A + (size_t)(m0 + srow) * lda + scol;
  const unsigned short* gB = Bt + (size_t)(n0 + srow) * ldb + scol;
  unsigned short* lA = lsA + tid * 8;
  unsigned short* lB = lsB + tid * 8;

  const int fr = lane & 15;
  const int j7 = lane & 7;
  const int g4 = lane >> 4;

  for (int k0 = 0; k0 < K; k0 += BK) {
    if (k0) __syncthreads();
    #pragma unroll
    for (int p = 0; p < PA; ++p)
      GLDS(gA + (size_t)(p * 32) * lda + k0, lA + p * 2048);
    #pragma unroll
    for (int p = 0; p < PB; ++p)
      GLDS(gB + (size_t)(p * 32) * ldb + k0, lB + p * 2048);
    __syncthreads();

    #pragma unroll
    for (int ks = 0; ks < 2; ++ks) {
      const int col = (((ks * 4 + g4) ^ j7) << 3);
      bf16x8 af[FM], bfv[FN];
      #pragma unroll
      for (int mi = 0; mi < FM; ++mi)
        af[mi] = *(const bf16x8*)&lsA[(wr * WM + mi * 16 + fr) * BK + col];
      #pragma unroll
      for (int nj = 0; nj < FN; ++nj)
        bfv[nj] = *(const bf16x8*)&lsB[(wc * WN + nj * 16 + fr) * BK + col];
      #pragma unroll
      for (int mi = 0; mi < FM; ++mi)
        #pragma unroll
        for (int nj = 0; nj < FN; ++nj)
          acc[mi][nj] = __builtin_amdgcn_mfma_f32_16x16x32_bf16(af[mi], bfv[nj], acc[mi][nj], 0, 0, 0);
    }
  }

  const int r0 = (lane >> 4) * 4, c0 = lane & 15;
  #pragma unroll
  for (int mi = 0; mi < FM; ++mi) {
    #pragma unroll
    for (int nj = 0; nj < FN; ++nj) {
      const int c = n0 + wc * WN + nj * 16 + c0;
      #pragma unroll
      for (int j = 0; j < 4; ++j) {
        const int r = m0 + wr * WM + mi * 16 + r0 + j;
        float v = acc[mi][nj][j];
        if (RELU) v = fmaxf(v, 0.0f);
        if (RESID) v += Res[(size_t)r * ldc + c];
        const size_t o = (size_t)r * ldc + c;
        if (BF16OUT) ((unsigned short*)Cv)[o] = f2b(v);
        else ((float*)Cv)[o] = v;
      }
    }
  }
}

extern "C" void kernel_launch(void* const* d_in, const int* in_sizes, int n_in,
                              void* d_out, int out_size, void* d_ws, size_t ws_size,
                              hipStream_t stream) {
  (void)in_sizes; (void)n_in; (void)out_size;
  const int*   idx      = (const int*)d_in[0];
  const float* tok_emb  = (const float*)d_in[1];
  const float* pos_emb  = (const float*)d_in[2];
  const float* q_proj   = (const float*)d_in[3];
  const float* kv_proj  = (const float*)d_in[4];
  const float* out_proj = (const float*)d_in[5];
  const float* fc_in    = (const float*)d_in[6];
  const float* fc_out   = (const float*)d_in[7];
  const float* scale    = (const float*)d_in[8];
  const float* out_scl  = (const float*)d_in[9];
  const float* lm_head  = (const float*)d_in[10];
  float* out = (float*)d_out;

  char* ws = (char*)d_ws;
  size_t off = 0;
  auto alloc = [&](size_t bytes) -> void* {
    void* p = ws + off;
    off += (bytes + 255) & ~(size_t)255;
    return p;
  };
  // [WqkvT(1536 rows) ; WoT(1024 rows)] contiguous (one batched transpose covers both)
  unsigned short* WqkvT = (unsigned short*)alloc((size_t)2560 * 1024 * 2);
  unsigned short* WoT   = WqkvT + (size_t)1536 * 1024;
  unsigned short* F1T   = (unsigned short*)alloc((size_t)4096 * 1024 * 2);
  unsigned short* F2T   = (unsigned short*)alloc((size_t)1024 * 4096 * 2);
  float*  xbuf  = (float*)alloc((size_t)2048 * 1024 * 4);
  float*  hbuf  = (float*)alloc((size_t)2048 * 1024 * 4);
  float*  h2buf = (float*)alloc((size_t)2048 * 1024 * 4);
  unsigned short* actb  = (unsigned short*)alloc((size_t)2048 * 1024 * 2);
  unsigned short* qkvb  = (unsigned short*)alloc((size_t)2048 * 1536 * 2);
  unsigned short* vT    = (unsigned short*)alloc((size_t)2 * 256 * 1024 * 2);
  unsigned short* LmT   = (unsigned short*)alloc((size_t)32000 * 1024 * 2);
  unsigned short* ob    = (unsigned short*)alloc((size_t)2048 * 1024 * 2);
  unsigned short* m1    = (unsigned short*)alloc((size_t)2048 * 4096 * 2);
  if (off > ws_size) return;

  const dim3 thr(256);

  embed_kernel<<<dim3(2048), thr, 0, stream>>>(idx, tok_emb, pos_emb, xbuf);

  for (int l = 0; l < 8; ++l) {
    const float* qp  = q_proj + (size_t)l * 1024 * 1024;
    const float* op  = out_proj + (size_t)l * 1024 * 1024;
    const float* kvp = kv_proj + (size_t)l * 2 * 1024 * 256;
    transpose_qkvo<<<dim3(2560), thr, 0, stream>>>(qp, op, kvp, WqkvT);
    transpose_fc<<<dim3(8192), thr, 0, stream>>>(
        fc_in + (size_t)l * 1024 * 4096, fc_out + (size_t)l * 4096 * 1024, F1T, F2T);

    const float* w1 = scale + (size_t)l * 2048;
    const float* w2 = w1 + 1024;

    ln_kernel<true><<<dim3(2048), thr, 0, stream>>>(xbuf, w1, hbuf, actb);
    gemm_nt<128, 64, true, false, false><<<dim3(16, 24), thr, 0, stream>>>(
        actb, WqkvT, qkvb, nullptr, 1024, 1024, 1024, 1536, 0);
    transpose_v<<<dim3(8, 32, 2), thr, 0, stream>>>(qkvb, vT);
    attn_fused<<<dim3(8, 32), thr, 0, stream>>>(qkvb, vT, ob);
    gemm_nt<128, 64, false, false, true><<<dim3(16, 16), thr, 0, stream>>>(
        ob, WoT, xbuf, hbuf, 1024, 1024, 1024, 1024, 0);
    ln_kernel<true><<<dim3(2048), thr, 0, stream>>>(xbuf, w2, h2buf, actb);
    gemm_nt<128, 128, true, true, false><<<dim3(16, 32), thr, 0, stream>>>(
        actb, F1T, m1, nullptr, 1024, 1024, 1024, 4096, 0);
    gemm_nt<128, 64, false, false, true><<<dim3(16, 16), thr, 0, stream>>>(
        m1, F2T, xbuf, h2buf, 4096, 4096, 4096, 1024, 0);
  }

  transpose_w<<<dim3(1000, 32), thr, 0, stream>>>(lm_head, LmT, 32000, 0, 1024);
  ln_kernel<false><<<dim3(2048), thr, 0, stream>>>(xbuf, out_scl, nullptr, actb);
  // logits: QUAD traversal, padded grid (16,256), 250 valid N-groups
  gemm_nt<128, 128, false, false, false, true><<<dim3(16, 256), thr, 0, stream>>>(
      actb, LmT, out, nullptr, 1024, 1024, 1024, 32000, 250);
}

// Round 12
// 1625.074 us; speedup vs baseline: 1.1359x; 1.0475x over previous
//
#include <hip/hip_runtime.h>
#include <hip/hip_bf16.h>

typedef __attribute__((ext_vector_type(8))) short bf16x8;
typedef __attribute__((ext_vector_type(4))) short bf16x4;
typedef __attribute__((ext_vector_type(4))) float f32x4;

#define LB __launch_bounds__(256)

__device__ __forceinline__ unsigned short f2b(float f) {
  __hip_bfloat16 h = __float2bfloat16(f);
  return __builtin_bit_cast(unsigned short, h);
}

// async global->LDS, 16B per lane. LDS dest must be wave-uniform base + lane*16.
#define GLDS(gp, lp)                                                        \
  __builtin_amdgcn_global_load_lds(                                         \
      (const __attribute__((address_space(1))) void*)(gp),                  \
      (__attribute__((address_space(3))) void*)(lp), 16, 0, 0)

// ---------------- embed ----------------
__global__ LB void embed_kernel(const int* __restrict__ idx, const float* __restrict__ tok,
                                const float* __restrict__ pos, float* __restrict__ X) {
  const int m = blockIdx.x;
  const int t = m & 1023;
  const int token = idx[m];
  const int c = threadIdx.x * 4;
  const float4 a = *(const float4*)(tok + (size_t)token * 1024 + c);
  const float4 p = *(const float4*)(pos + (size_t)t * 1024 + c);
  float4 o; o.x = a.x + p.x; o.y = a.y + p.y; o.z = a.z + p.z; o.w = a.w + p.w;
  *(float4*)(X + (size_t)m * 1024 + c) = o;
}

// ---------------- layernorm ----------------
template<bool WF32>
__global__ LB void ln_kernel(const float* __restrict__ X, const float* __restrict__ W,
                             float* __restrict__ Yf, unsigned short* __restrict__ Yb) {
  const int row = blockIdx.x;
  const float* xr = X + (size_t)row * 1024;
  const int c = threadIdx.x * 4;
  const float4 v = *(const float4*)(xr + c);
  float s = v.x + v.y + v.z + v.w;
  float q = v.x*v.x + v.y*v.y + v.z*v.z + v.w*v.w;
  #pragma unroll
  for (int d = 32; d > 0; d >>= 1) { s += __shfl_down(s, d); q += __shfl_down(q, d); }
  __shared__ float ss[4], sq[4];
  const int wid = threadIdx.x >> 6;
  if ((threadIdx.x & 63) == 0) { ss[wid] = s; sq[wid] = q; }
  __syncthreads();
  const float fs = ss[0] + ss[1] + ss[2] + ss[3];
  const float fq = sq[0] + sq[1] + sq[2] + sq[3];
  const float mean = fs * (1.0f / 1024.0f);
  const float var = fq * (1.0f / 1024.0f) - mean * mean;
  const float rstd = rsqrtf(var + 1e-5f);
  const float4 w = *(const float4*)(W + c);
  float4 o;
  o.x = (v.x - mean) * rstd * w.x; o.y = (v.y - mean) * rstd * w.y;
  o.z = (v.z - mean) * rstd * w.z; o.w = (v.w - mean) * rstd * w.w;
  if (WF32) *(float4*)(Yf + (size_t)row * 1024 + c) = o;
  unsigned long long pk = (unsigned long long)f2b(o.x)
      | ((unsigned long long)f2b(o.y) << 16)
      | ((unsigned long long)f2b(o.z) << 32)
      | ((unsigned long long)f2b(o.w) << 48);
  *(unsigned long long*)(Yb + (size_t)row * 1024 + c) = pk;
}

// ---------------- transpose tile body: dst[rowOff+c][r] = bf16(src[r][c]) ----------------
__device__ __forceinline__ void tr_body(const float* __restrict__ src,
                                        unsigned short* __restrict__ dst,
                                        int C, int rowOff, int ldDst, int bx, int by) {
  __shared__ float tile[32][33];
  const int c0 = bx * 32, r0 = by * 32;
  const int tx = threadIdx.x & 31, ty = threadIdx.x >> 5;
  #pragma unroll
  for (int u = 0; u < 4; ++u)
    tile[ty + u * 8][tx] = src[(size_t)(r0 + ty + u * 8) * C + c0 + tx];
  __syncthreads();
  const int ci = threadIdx.x >> 4;
  const int rp = threadIdx.x & 15;
  #pragma unroll
  for (int u = 0; u < 2; ++u) {
    const int c = ci + u * 16;
    unsigned int pk = (unsigned int)f2b(tile[rp * 2][c])
                    | ((unsigned int)f2b(tile[rp * 2 + 1][c]) << 16);
    *(unsigned int*)&dst[(size_t)(rowOff + c0 + c) * ldDst + r0 + rp * 2] = pk;
  }
}

// lm_head transpose (standalone)
__global__ LB void transpose_w(const float* __restrict__ src, unsigned short* __restrict__ dst,
                               int C, int rowOff, int ldDst) {
  tr_body(src, dst, C, rowOff, ldDst, blockIdx.x, blockIdx.y);
}

// batched q/out/k/v transpose: 2560 flat blocks
__global__ LB void transpose_qkvo(const float* __restrict__ qp, const float* __restrict__ op,
                                  const float* __restrict__ kvp, unsigned short* __restrict__ dst) {
  int id = blockIdx.x;
  const float* src; int C, rowOff, bx, by;
  if (id < 2048) {
    src = (id < 1024) ? qp : op;
    rowOff = (id < 1024) ? 0 : 1536;
    id &= 1023; C = 1024; bx = id & 31; by = id >> 5;
  } else {
    id -= 2048;
    src = (id < 256) ? kvp : (kvp + 1024 * 256);
    rowOff = (id < 256) ? 1024 : 1280;
    id &= 255; C = 256; bx = id & 7; by = id >> 3;
  }
  tr_body(src, dst, C, rowOff, 1024, bx, by);
}

// batched fc1/fc2 transpose: 8192 flat blocks
__global__ LB void transpose_fc(const float* __restrict__ f1, const float* __restrict__ f2,
                                unsigned short* __restrict__ F1T, unsigned short* __restrict__ F2T) {
  int id = blockIdx.x;
  if (id < 4096) {
    tr_body(f1, F1T, 4096, 0, 1024, id & 127, id >> 7);
  } else {
    id -= 4096;
    tr_body(f2, F2T, 1024, 0, 4096, id & 31, id >> 5);
  }
}

// ---------------- v transpose: vT[b][n*64+d][t] ----------------
__global__ LB void transpose_v(const unsigned short* __restrict__ src, unsigned short* __restrict__ dst) {
  __shared__ unsigned short tile[32][33];
  const int b = blockIdx.z;
  const int c0 = blockIdx.x * 32, t0 = blockIdx.y * 32;
  const int tx = threadIdx.x & 31, ty = threadIdx.x >> 5;
  #pragma unroll
  for (int u = 0; u < 4; ++u)
    tile[ty + u * 8][tx] = src[(size_t)(b * 1024 + t0 + ty + u * 8) * 1536 + 1280 + c0 + tx];
  __syncthreads();
  #pragma unroll
  for (int u = 0; u < 4; ++u)
    dst[((size_t)b * 256 + c0 + ty + u * 8) * 1024 + t0 + tx] = tile[tx][ty + u * 8];
}

// ---------------- fused flash attention: dbuf K/V, 64-row q-tiles, 2 blocks/CU ----------------
// Grid (16 q-tiles of 64, 32 b*head); heavy tiles (qt=15) first. 4 waves, wave w
// owns q rows [qt*64+w*16, +16); kdiag == qt uniform. Double-buffered K/V staged
// via GLDS (XOR chunk swizzle); prefetch of kt+1 issued before compute of kt, one
// __syncthreads per iteration (vmcnt drain lands after compute). P via per-wave
// swizzled LDS. Swapped QK^T: st = mfma(K, Q) holds S^T[k][q=c].
__global__ LB void attn_fused(const unsigned short* __restrict__ qkvb,
                              const unsigned short* __restrict__ vT,
                              unsigned short* __restrict__ ob) {
  const int qt = 15 - blockIdx.x, bh = blockIdx.y;
  const int b = bh >> 4, hh = bh & 15, n = hh & 3;
  const int tid = threadIdx.x, lane = tid & 63, w = tid >> 6;
  const int g = lane >> 4, c = lane & 15;
  const int q0w = qt * 64 + w * 16;
  const int qrow = q0w + c;

  __shared__ unsigned short lsK[2][64 * 64];
  __shared__ unsigned short lsV[2][64 * 64];
  __shared__ unsigned short lsP[4][16 * 64];
  unsigned short* Pw = lsP[w];

  // Q fragments (B operand): lane: q-col = c, d-chunk = ks*32+g*8
  bf16x8 qf[2];
  {
    const unsigned short* Qb = qkvb + (size_t)(b * 1024 + q0w) * 1536 + hh * 64;
    #pragma unroll
    for (int ks = 0; ks < 2; ++ks)
      qf[ks] = *(const bf16x8*)(Qb + (size_t)c * 1536 + ks * 32 + g * 8);
  }

  f32x4 accO[4] = {};                    // O[q=g*4+j][d=dj*16+c]
  float mr = -1e30f, lr = 0.0f;

  // staging: thread t -> LDS linear row=t/8(+32), chunk=t&7; global col pre-swizzled
  const int srow = tid >> 3;
  const int scol = ((tid & 7) ^ (srow & 7)) << 3;
  const unsigned short* gK = qkvb + (size_t)(b * 1024 + srow) * 1536 + 1024 + n * 64 + scol;
  const unsigned short* gV = vT + (size_t)((b * 4 + n) * 64 + srow) * 1024 + scol;

  // prologue: stage tile 0 into buffer 0
  GLDS(gK, &lsK[0][tid * 8]);
  GLDS(gK + (size_t)32 * 1536, &lsK[0][tid * 8 + 2048]);
  GLDS(gV, &lsV[0][tid * 8]);
  GLDS(gV + (size_t)32 * 1024, &lsV[0][tid * 8 + 2048]);
  __syncthreads();

  for (int kt = 0; kt <= qt; ++kt) {
    const int cur = kt & 1;
    if (kt < qt) {                       // prefetch kt+1 into other buffer (no wait)
      const size_t ko = (size_t)(kt + 1) * 64;
      GLDS(gK + ko * 1536, &lsK[cur ^ 1][tid * 8]);
      GLDS(gK + (ko + 32) * 1536, &lsK[cur ^ 1][tid * 8 + 2048]);
      GLDS(gV + ko, &lsV[cur ^ 1][tid * 8]);
      GLDS(gV + ko + (size_t)32 * 1024, &lsV[cur ^ 1][tid * 8 + 2048]);
    }
    const unsigned short* K_ = lsK[cur];
    const unsigned short* V_ = lsV[cur];
    const bool dg = (kt == qt);
    const int kb = kt * 64;

    // S^T[k = mi*16+g*4+j][q = c]
    f32x4 st[4] = {};
    #pragma unroll
    for (int ks = 0; ks < 2; ++ks) {
      const int col = (((ks * 4 + g) ^ (lane & 7)) << 3);
      bf16x8 kf[4];
      #pragma unroll
      for (int mi = 0; mi < 4; ++mi)
        kf[mi] = *(const bf16x8*)&K_[(mi * 16 + c) * 64 + col];
      #pragma unroll
      for (int mi = 0; mi < 4; ++mi)
        st[mi] = __builtin_amdgcn_mfma_f32_16x16x32_bf16(kf[mi], qf[ks], st[mi], 0, 0, 0);
    }

    // online softmax for q = c (reduce over g-lanes)
    float mx = mr;
    #pragma unroll
    for (int mi = 0; mi < 4; ++mi)
      #pragma unroll
      for (int j = 0; j < 4; ++j) {
        float v = st[mi][j] * 0.125f;
        if (dg && (kb + mi * 16 + g * 4 + j) > qrow) v = -1e30f;
        st[mi][j] = v;
        mx = fmaxf(mx, v);
      }
    mx = fmaxf(mx, __shfl_xor(mx, 16));
    mx = fmaxf(mx, __shfl_xor(mx, 32));
    const float al = __expf(mr - mx);
    float sum = 0.0f;
    #pragma unroll
    for (int mi = 0; mi < 4; ++mi) {
      bf16x4 pk;
      #pragma unroll
      for (int j = 0; j < 4; ++j) {
        const float e = __expf(st[mi][j] - mx);
        sum += e;
        pk[j] = (short)f2b(e);
      }
      // P[q=c][k]: 4 k-contiguous; 16B-chunk XOR by c&7
      *(bf16x4*)&Pw[c * 64 + ((mi * 16 + g * 4) ^ ((c & 7) << 3))] = pk;
    }
    sum += __shfl_xor(sum, 16);
    sum += __shfl_xor(sum, 32);
    lr = lr * al + sum;
    mr = mx;

    // rescale O rows (row q-local = g*4+j; alpha lives at lane c = g*4+j)
    float aj[4];
    #pragma unroll
    for (int j = 0; j < 4; ++j) aj[j] = __shfl(al, g * 4 + j);
    #pragma unroll
    for (int dj = 0; dj < 4; ++dj)
      #pragma unroll
      for (int j = 0; j < 4; ++j) accO[dj][j] *= aj[j];

    // O += P·V
    #pragma unroll
    for (int ks = 0; ks < 2; ++ks) {
      const int col = (((ks * 4 + g) ^ (c & 7)) << 3);
      const bf16x8 pa = *(const bf16x8*)&Pw[c * 64 + col];
      bf16x8 vf[4];
      #pragma unroll
      for (int dj = 0; dj < 4; ++dj)
        vf[dj] = *(const bf16x8*)&V_[(dj * 16 + c) * 64 + col];
      #pragma unroll
      for (int dj = 0; dj < 4; ++dj)
        accO[dj] = __builtin_amdgcn_mfma_f32_16x16x32_bf16(pa, vf[dj], accO[dj], 0, 0, 0);
    }
    __syncthreads();   // drains prefetch; all waves done reading K_/V_/P
  }

  const float linv = 1.0f / lr;
  float lj[4];
  #pragma unroll
  for (int j = 0; j < 4; ++j) lj[j] = __shfl(linv, g * 4 + j);
  unsigned short* obase = ob + (size_t)(b * 1024 + q0w) * 1024 + hh * 64;
  #pragma unroll
  for (int dj = 0; dj < 4; ++dj)
    #pragma unroll
    for (int j = 0; j < 4; ++j)
      obase[(size_t)(g * 4 + j) * 1024 + dj * 16 + c] = f2b(accO[dj][j] * lj[j]);
}

// ---------------- NT GEMM: C = A[M,K]*Bt[N,K]^T, bf16 in, f32 acc ----------------
// BK=64, XOR chunk swizzle; bx=M-tile fastest + XCD chunk swizzle.
template<int BM, int BN, bool BF16OUT, bool RELU, bool RESID>
__global__ LB void gemm_nt(const unsigned short* __restrict__ A, const unsigned short* __restrict__ Bt,
                           void* __restrict__ Cv, const float* __restrict__ Res,
                           int K, int lda, int ldb, int ldc) {
  constexpr int BK = 64;
  constexpr int WM = BM / 2, WN = BN / 2;
  constexpr int FM = WM / 16, FN = WN / 16;
  constexpr int PA = BM / 32, PB = BN / 32;
  int f = blockIdx.x + gridDim.x * blockIdx.y;
  const int nwg = gridDim.x * gridDim.y;
  if ((nwg & 7) == 0) f = (f & 7) * (nwg >> 3) + (f >> 3);
  const int bx = f % gridDim.x, by = f / gridDim.x;

  const int tid = threadIdx.x;
  const int lane = tid & 63, wid = tid >> 6;
  const int wr = wid >> 1, wc = wid & 1;
  const int m0 = bx * BM, n0 = by * BN;

  __shared__ unsigned short lsA[BM * BK];
  __shared__ unsigned short lsB[BN * BK];

  f32x4 acc[FM][FN] = {};

  const int srow = tid >> 3;
  const int scol = ((tid & 7) ^ (srow & 7)) << 3;
  const unsigned short* gA = A + (size_t)(m0 + srow) * lda + scol;
  const unsigned short* gB = Bt + (size_t)(n0 + srow) * ldb + scol;
  unsigned short* lA = lsA + tid * 8;
  unsigned short* lB = lsB + tid * 8;

  const int fr = lane & 15;
  const int j7 = lane & 7;
  const int g4 = lane >> 4;

  for (int k0 = 0; k0 < K; k0 += BK) {
    if (k0) __syncthreads();
    #pragma unroll
    for (int p = 0; p < PA; ++p)
      GLDS(gA + (size_t)(p * 32) * lda + k0, lA + p * 2048);
    #pragma unroll
    for (int p = 0; p < PB; ++p)
      GLDS(gB + (size_t)(p * 32) * ldb + k0, lB + p * 2048);
    __syncthreads();

    #pragma unroll
    for (int ks = 0; ks < 2; ++ks) {
      const int col = (((ks * 4 + g4) ^ j7) << 3);
      bf16x8 af[FM], bfv[FN];
      #pragma unroll
      for (int mi = 0; mi < FM; ++mi)
        af[mi] = *(const bf16x8*)&lsA[(wr * WM + mi * 16 + fr) * BK + col];
      #pragma unroll
      for (int nj = 0; nj < FN; ++nj)
        bfv[nj] = *(const bf16x8*)&lsB[(wc * WN + nj * 16 + fr) * BK + col];
      #pragma unroll
      for (int mi = 0; mi < FM; ++mi)
        #pragma unroll
        for (int nj = 0; nj < FN; ++nj)
          acc[mi][nj] = __builtin_amdgcn_mfma_f32_16x16x32_bf16(af[mi], bfv[nj], acc[mi][nj], 0, 0, 0);
    }
  }

  const int r0 = (lane >> 4) * 4, c0 = lane & 15;
  #pragma unroll
  for (int mi = 0; mi < FM; ++mi) {
    #pragma unroll
    for (int nj = 0; nj < FN; ++nj) {
      const int c = n0 + wc * WN + nj * 16 + c0;
      #pragma unroll
      for (int j = 0; j < 4; ++j) {
        const int r = m0 + wr * WM + mi * 16 + r0 + j;
        float v = acc[mi][nj][j];
        if (RELU) v = fmaxf(v, 0.0f);
        if (RESID) v += Res[(size_t)r * ldc + c];
        const size_t o = (size_t)r * ldc + c;
        if (BF16OUT) ((unsigned short*)Cv)[o] = f2b(v);
        else ((float*)Cv)[o] = v;
      }
    }
  }
}

extern "C" void kernel_launch(void* const* d_in, const int* in_sizes, int n_in,
                              void* d_out, int out_size, void* d_ws, size_t ws_size,
                              hipStream_t stream) {
  (void)in_sizes; (void)n_in; (void)out_size;
  const int*   idx      = (const int*)d_in[0];
  const float* tok_emb  = (const float*)d_in[1];
  const float* pos_emb  = (const float*)d_in[2];
  const float* q_proj   = (const float*)d_in[3];
  const float* kv_proj  = (const float*)d_in[4];
  const float* out_proj = (const float*)d_in[5];
  const float* fc_in    = (const float*)d_in[6];
  const float* fc_out   = (const float*)d_in[7];
  const float* scale    = (const float*)d_in[8];
  const float* out_scl  = (const float*)d_in[9];
  const float* lm_head  = (const float*)d_in[10];
  float* out = (float*)d_out;

  char* ws = (char*)d_ws;
  size_t off = 0;
  auto alloc = [&](size_t bytes) -> void* {
    void* p = ws + off;
    off += (bytes + 255) & ~(size_t)255;
    return p;
  };
  // [WqkvT(1536 rows) ; WoT(1024 rows)] contiguous (one batched transpose covers both)
  unsigned short* WqkvT = (unsigned short*)alloc((size_t)2560 * 1024 * 2);
  unsigned short* WoT   = WqkvT + (size_t)1536 * 1024;
  unsigned short* F1T   = (unsigned short*)alloc((size_t)4096 * 1024 * 2);
  unsigned short* F2T   = (unsigned short*)alloc((size_t)1024 * 4096 * 2);
  float*  xbuf  = (float*)alloc((size_t)2048 * 1024 * 4);
  float*  hbuf  = (float*)alloc((size_t)2048 * 1024 * 4);
  float*  h2buf = (float*)alloc((size_t)2048 * 1024 * 4);
  unsigned short* actb  = (unsigned short*)alloc((size_t)2048 * 1024 * 2);
  unsigned short* qkvb  = (unsigned short*)alloc((size_t)2048 * 1536 * 2);
  unsigned short* vT    = (unsigned short*)alloc((size_t)2 * 256 * 1024 * 2);
  unsigned short* LmT   = (unsigned short*)alloc((size_t)32000 * 1024 * 2);
  unsigned short* ob    = (unsigned short*)alloc((size_t)2048 * 1024 * 2);
  unsigned short* m1    = (unsigned short*)alloc((size_t)2048 * 4096 * 2);
  if (off > ws_size) return;

  const dim3 thr(256);

  embed_kernel<<<dim3(2048), thr, 0, stream>>>(idx, tok_emb, pos_emb, xbuf);

  for (int l = 0; l < 8; ++l) {
    const float* qp  = q_proj + (size_t)l * 1024 * 1024;
    const float* op  = out_proj + (size_t)l * 1024 * 1024;
    const float* kvp = kv_proj + (size_t)l * 2 * 1024 * 256;
    transpose_qkvo<<<dim3(2560), thr, 0, stream>>>(qp, op, kvp, WqkvT);
    transpose_fc<<<dim3(8192), thr, 0, stream>>>(
        fc_in + (size_t)l * 1024 * 4096, fc_out + (size_t)l * 4096 * 1024, F1T, F2T);

    const float* w1 = scale + (size_t)l * 2048;
    const float* w2 = w1 + 1024;

    ln_kernel<true><<<dim3(2048), thr, 0, stream>>>(xbuf, w1, hbuf, actb);
    gemm_nt<128, 64, true, false, false><<<dim3(16, 24), thr, 0, stream>>>(
        actb, WqkvT, qkvb, nullptr, 1024, 1024, 1024, 1536);
    transpose_v<<<dim3(8, 32, 2), thr, 0, stream>>>(qkvb, vT);
    attn_fused<<<dim3(16, 32), thr, 0, stream>>>(qkvb, vT, ob);
    gemm_nt<128, 64, false, false, true><<<dim3(16, 16), thr, 0, stream>>>(
        ob, WoT, xbuf, hbuf, 1024, 1024, 1024, 1024);
    ln_kernel<true><<<dim3(2048), thr, 0, stream>>>(xbuf, w2, h2buf, actb);
    gemm_nt<128, 128, true, true, false><<<dim3(16, 32), thr, 0, stream>>>(
        actb, F1T, m1, nullptr, 1024, 1024, 1024, 4096);
    gemm_nt<128, 64, false, false, true><<<dim3(16, 16), thr, 0, stream>>>(
        m1, F2T, xbuf, h2buf, 4096, 4096, 4096, 1024);
  }

  transpose_w<<<dim3(1000, 32), thr, 0, stream>>>(lm_head, LmT, 32000, 0, 1024);
  ln_kernel<false><<<dim3(2048), thr, 0, stream>>>(xbuf, out_scl, nullptr, actb);
  gemm_nt<128, 128, false, false, false><<<dim3(16, 250), thr, 0, stream>>>(
      actb, LmT, out, nullptr, 1024, 1024, 1024, 32000);
}

// Round 13
// 1608.247 us; speedup vs baseline: 1.1478x; 1.0105x over previous
//
#include <hip/hip_runtime.h>
#include <hip/hip_bf16.h>

typedef __attribute__((ext_vector_type(8))) short bf16x8;
typedef __attribute__((ext_vector_type(4))) short bf16x4;
typedef __attribute__((ext_vector_type(4))) float f32x4;

#define LB __launch_bounds__(256)

__device__ __forceinline__ unsigned short f2b(float f) {
  __hip_bfloat16 h = __float2bfloat16(f);
  return __builtin_bit_cast(unsigned short, h);
}

// async global->LDS, 16B per lane. LDS dest must be wave-uniform base + lane*16.
#define GLDS(gp, lp)                                                        \
  __builtin_amdgcn_global_load_lds(                                         \
      (const __attribute__((address_space(1))) void*)(gp),                  \
      (__attribute__((address_space(3))) void*)(lp), 16, 0, 0)

// ---------------- embed ----------------
__global__ LB void embed_kernel(const int* __restrict__ idx, const float* __restrict__ tok,
                                const float* __restrict__ pos, float* __restrict__ X) {
  const int m = blockIdx.x;
  const int t = m & 1023;
  const int token = idx[m];
  const int c = threadIdx.x * 4;
  const float4 a = *(const float4*)(tok + (size_t)token * 1024 + c);
  const float4 p = *(const float4*)(pos + (size_t)t * 1024 + c);
  float4 o; o.x = a.x + p.x; o.y = a.y + p.y; o.z = a.z + p.z; o.w = a.w + p.w;
  *(float4*)(X + (size_t)m * 1024 + c) = o;
}

// ---------------- layernorm ----------------
template<bool WF32>
__global__ LB void ln_kernel(const float* __restrict__ X, const float* __restrict__ W,
                             float* __restrict__ Yf, unsigned short* __restrict__ Yb) {
  const int row = blockIdx.x;
  const float* xr = X + (size_t)row * 1024;
  const int c = threadIdx.x * 4;
  const float4 v = *(const float4*)(xr + c);
  float s = v.x + v.y + v.z + v.w;
  float q = v.x*v.x + v.y*v.y + v.z*v.z + v.w*v.w;
  #pragma unroll
  for (int d = 32; d > 0; d >>= 1) { s += __shfl_down(s, d); q += __shfl_down(q, d); }
  __shared__ float ss[4], sq[4];
  const int wid = threadIdx.x >> 6;
  if ((threadIdx.x & 63) == 0) { ss[wid] = s; sq[wid] = q; }
  __syncthreads();
  const float fs = ss[0] + ss[1] + ss[2] + ss[3];
  const float fq = sq[0] + sq[1] + sq[2] + sq[3];
  const float mean = fs * (1.0f / 1024.0f);
  const float var = fq * (1.0f / 1024.0f) - mean * mean;
  const float rstd = rsqrtf(var + 1e-5f);
  const float4 w = *(const float4*)(W + c);
  float4 o;
  o.x = (v.x - mean) * rstd * w.x; o.y = (v.y - mean) * rstd * w.y;
  o.z = (v.z - mean) * rstd * w.z; o.w = (v.w - mean) * rstd * w.w;
  if (WF32) *(float4*)(Yf + (size_t)row * 1024 + c) = o;
  unsigned long long pk = (unsigned long long)f2b(o.x)
      | ((unsigned long long)f2b(o.y) << 16)
      | ((unsigned long long)f2b(o.z) << 32)
      | ((unsigned long long)f2b(o.w) << 48);
  *(unsigned long long*)(Yb + (size_t)row * 1024 + c) = pk;
}

// ---------------- transpose tile body: dst[rowOff+c][r] = bf16(src[r][c]) ----------------
__device__ __forceinline__ void tr_body(const float* __restrict__ src,
                                        unsigned short* __restrict__ dst,
                                        int C, int rowOff, int ldDst, int bx, int by) {
  __shared__ float tile[32][33];
  const int c0 = bx * 32, r0 = by * 32;
  const int tx = threadIdx.x & 31, ty = threadIdx.x >> 5;
  #pragma unroll
  for (int u = 0; u < 4; ++u)
    tile[ty + u * 8][tx] = src[(size_t)(r0 + ty + u * 8) * C + c0 + tx];
  __syncthreads();
  const int ci = threadIdx.x >> 4;
  const int rp = threadIdx.x & 15;
  #pragma unroll
  for (int u = 0; u < 2; ++u) {
    const int c = ci + u * 16;
    unsigned int pk = (unsigned int)f2b(tile[rp * 2][c])
                    | ((unsigned int)f2b(tile[rp * 2 + 1][c]) << 16);
    *(unsigned int*)&dst[(size_t)(rowOff + c0 + c) * ldDst + r0 + rp * 2] = pk;
  }
}

// lm_head transpose (standalone)
__global__ LB void transpose_w(const float* __restrict__ src, unsigned short* __restrict__ dst,
                               int C, int rowOff, int ldDst) {
  tr_body(src, dst, C, rowOff, ldDst, blockIdx.x, blockIdx.y);
}

// all per-layer weight transposes in ONE launch: 10752 flat blocks
// [0,1024): q -> rows 0..1023    [1024,2048): out -> rows 1536..2559
// [2048,2304): k -> 1024..1279   [2304,2560): v -> 1280..1535
// [2560,6656): fc1 [1024x4096] -> F1T   [6656,10752): fc2 [4096x1024] -> F2T
__global__ LB void transpose_all(const float* __restrict__ qp, const float* __restrict__ op,
                                 const float* __restrict__ kvp, unsigned short* __restrict__ dstQ,
                                 const float* __restrict__ f1, const float* __restrict__ f2,
                                 unsigned short* __restrict__ F1T, unsigned short* __restrict__ F2T) {
  int id = blockIdx.x;
  if (id < 2560) {
    const float* src; int C, rowOff, bx, by;
    if (id < 2048) {
      src = (id < 1024) ? qp : op;
      rowOff = (id < 1024) ? 0 : 1536;
      id &= 1023; C = 1024; bx = id & 31; by = id >> 5;
    } else {
      id -= 2048;
      src = (id < 256) ? kvp : (kvp + 1024 * 256);
      rowOff = (id < 256) ? 1024 : 1280;
      id &= 255; C = 256; bx = id & 7; by = id >> 3;
    }
    tr_body(src, dstQ, C, rowOff, 1024, bx, by);
  } else {
    id -= 2560;
    if (id < 4096) {
      tr_body(f1, F1T, 4096, 0, 1024, id & 127, id >> 7);
    } else {
      id -= 4096;
      tr_body(f2, F2T, 1024, 0, 4096, id & 31, id >> 5);
    }
  }
}

// ---------------- fused flash attention: dbuf K/V, 64-row q-tiles, 2 blocks/CU ----------------
__global__ LB void attn_fused(const unsigned short* __restrict__ qkvb,
                              const unsigned short* __restrict__ vT,
                              unsigned short* __restrict__ ob) {
  const int qt = 15 - blockIdx.x, bh = blockIdx.y;
  const int b = bh >> 4, hh = bh & 15, n = hh & 3;
  const int tid = threadIdx.x, lane = tid & 63, w = tid >> 6;
  const int g = lane >> 4, c = lane & 15;
  const int q0w = qt * 64 + w * 16;
  const int qrow = q0w + c;

  __shared__ unsigned short lsK[2][64 * 64];
  __shared__ unsigned short lsV[2][64 * 64];
  __shared__ unsigned short lsP[4][16 * 64];
  unsigned short* Pw = lsP[w];

  bf16x8 qf[2];
  {
    const unsigned short* Qb = qkvb + (size_t)(b * 1024 + q0w) * 1536 + hh * 64;
    #pragma unroll
    for (int ks = 0; ks < 2; ++ks)
      qf[ks] = *(const bf16x8*)(Qb + (size_t)c * 1536 + ks * 32 + g * 8);
  }

  f32x4 accO[4] = {};
  float mr = -1e30f, lr = 0.0f;

  const int srow = tid >> 3;
  const int scol = ((tid & 7) ^ (srow & 7)) << 3;
  const unsigned short* gK = qkvb + (size_t)(b * 1024 + srow) * 1536 + 1024 + n * 64 + scol;
  const unsigned short* gV = vT + (size_t)((b * 4 + n) * 64 + srow) * 1024 + scol;

  GLDS(gK, &lsK[0][tid * 8]);
  GLDS(gK + (size_t)32 * 1536, &lsK[0][tid * 8 + 2048]);
  GLDS(gV, &lsV[0][tid * 8]);
  GLDS(gV + (size_t)32 * 1024, &lsV[0][tid * 8 + 2048]);
  __syncthreads();

  for (int kt = 0; kt <= qt; ++kt) {
    const int cur = kt & 1;
    if (kt < qt) {
      const size_t ko = (size_t)(kt + 1) * 64;
      GLDS(gK + ko * 1536, &lsK[cur ^ 1][tid * 8]);
      GLDS(gK + (ko + 32) * 1536, &lsK[cur ^ 1][tid * 8 + 2048]);
      GLDS(gV + ko, &lsV[cur ^ 1][tid * 8]);
      GLDS(gV + ko + (size_t)32 * 1024, &lsV[cur ^ 1][tid * 8 + 2048]);
    }
    const unsigned short* K_ = lsK[cur];
    const unsigned short* V_ = lsV[cur];
    const bool dg = (kt == qt);
    const int kb = kt * 64;

    f32x4 st[4] = {};
    #pragma unroll
    for (int ks = 0; ks < 2; ++ks) {
      const int col = (((ks * 4 + g) ^ (lane & 7)) << 3);
      bf16x8 kf[4];
      #pragma unroll
      for (int mi = 0; mi < 4; ++mi)
        kf[mi] = *(const bf16x8*)&K_[(mi * 16 + c) * 64 + col];
      #pragma unroll
      for (int mi = 0; mi < 4; ++mi)
        st[mi] = __builtin_amdgcn_mfma_f32_16x16x32_bf16(kf[mi], qf[ks], st[mi], 0, 0, 0);
    }

    float mx = mr;
    #pragma unroll
    for (int mi = 0; mi < 4; ++mi)
      #pragma unroll
      for (int j = 0; j < 4; ++j) {
        float v = st[mi][j] * 0.125f;
        if (dg && (kb + mi * 16 + g * 4 + j) > qrow) v = -1e30f;
        st[mi][j] = v;
        mx = fmaxf(mx, v);
      }
    mx = fmaxf(mx, __shfl_xor(mx, 16));
    mx = fmaxf(mx, __shfl_xor(mx, 32));
    const float al = __expf(mr - mx);
    float sum = 0.0f;
    #pragma unroll
    for (int mi = 0; mi < 4; ++mi) {
      bf16x4 pk;
      #pragma unroll
      for (int j = 0; j < 4; ++j) {
        const float e = __expf(st[mi][j] - mx);
        sum += e;
        pk[j] = (short)f2b(e);
      }
      *(bf16x4*)&Pw[c * 64 + ((mi * 16 + g * 4) ^ ((c & 7) << 3))] = pk;
    }
    sum += __shfl_xor(sum, 16);
    sum += __shfl_xor(sum, 32);
    lr = lr * al + sum;
    mr = mx;

    float aj[4];
    #pragma unroll
    for (int j = 0; j < 4; ++j) aj[j] = __shfl(al, g * 4 + j);
    #pragma unroll
    for (int dj = 0; dj < 4; ++dj)
      #pragma unroll
      for (int j = 0; j < 4; ++j) accO[dj][j] *= aj[j];

    #pragma unroll
    for (int ks = 0; ks < 2; ++ks) {
      const int col = (((ks * 4 + g) ^ (c & 7)) << 3);
      const bf16x8 pa = *(const bf16x8*)&Pw[c * 64 + col];
      bf16x8 vf[4];
      #pragma unroll
      for (int dj = 0; dj < 4; ++dj)
        vf[dj] = *(const bf16x8*)&V_[(dj * 16 + c) * 64 + col];
      #pragma unroll
      for (int dj = 0; dj < 4; ++dj)
        accO[dj] = __builtin_amdgcn_mfma_f32_16x16x32_bf16(pa, vf[dj], accO[dj], 0, 0, 0);
    }
    __syncthreads();
  }

  const float linv = 1.0f / lr;
  float lj[4];
  #pragma unroll
  for (int j = 0; j < 4; ++j) lj[j] = __shfl(linv, g * 4 + j);
  unsigned short* obase = ob + (size_t)(b * 1024 + q0w) * 1024 + hh * 64;
  #pragma unroll
  for (int dj = 0; dj < 4; ++dj)
    #pragma unroll
    for (int j = 0; j < 4; ++j)
      obase[(size_t)(g * 4 + j) * 1024 + dj * 16 + c] = f2b(accO[dj][j] * lj[j]);
}

// ---------------- NT GEMM: C = A[M,K]*Bt[N,K]^T, bf16 in, f32 acc ----------------
// BK=64, XOR chunk swizzle; bx=M-tile fastest + XCD chunk swizzle.
// WVT: for output cols >=1280 (V part of qkv) also write vT[b][c-1280][t] packed (R6-verified).
template<int BM, int BN, bool BF16OUT, bool RELU, bool RESID, bool WVT = false>
__global__ LB void gemm_nt(const unsigned short* __restrict__ A, const unsigned short* __restrict__ Bt,
                           void* __restrict__ Cv, const float* __restrict__ Res,
                           unsigned short* __restrict__ vTo,
                           int K, int lda, int ldb, int ldc) {
  constexpr int BK = 64;
  constexpr int WM = BM / 2, WN = BN / 2;
  constexpr int FM = WM / 16, FN = WN / 16;
  constexpr int PA = BM / 32, PB = BN / 32;
  int f = blockIdx.x + gridDim.x * blockIdx.y;
  const int nwg = gridDim.x * gridDim.y;
  if ((nwg & 7) == 0) f = (f & 7) * (nwg >> 3) + (f >> 3);
  const int bx = f % gridDim.x, by = f / gridDim.x;

  const int tid = threadIdx.x;
  const int lane = tid & 63, wid = tid >> 6;
  const int wr = wid >> 1, wc = wid & 1;
  const int m0 = bx * BM, n0 = by * BN;

  __shared__ unsigned short lsA[BM * BK];
  __shared__ unsigned short lsB[BN * BK];

  f32x4 acc[FM][FN] = {};

  const int srow = tid >> 3;
  const int scol = ((tid & 7) ^ (srow & 7)) << 3;
  const unsigned short* gA = A + (size_t)(m0 + srow) * lda + scol;
  const unsigned short* gB = Bt + (size_t)(n0 + srow) * ldb + scol;
  unsigned short* lA = lsA + tid * 8;
  unsigned short* lB = lsB + tid * 8;

  const int fr = lane & 15;
  const int j7 = lane & 7;
  const int g4 = lane >> 4;

  for (int k0 = 0; k0 < K; k0 += BK) {
    if (k0) __syncthreads();
    #pragma unroll
    for (int p = 0; p < PA; ++p)
      GLDS(gA + (size_t)(p * 32) * lda + k0, lA + p * 2048);
    #pragma unroll
    for (int p = 0; p < PB; ++p)
      GLDS(gB + (size_t)(p * 32) * ldb + k0, lB + p * 2048);
    __syncthreads();

    #pragma unroll
    for (int ks = 0; ks < 2; ++ks) {
      const int col = (((ks * 4 + g4) ^ j7) << 3);
      bf16x8 af[FM], bfv[FN];
      #pragma unroll
      for (int mi = 0; mi < FM; ++mi)
        af[mi] = *(const bf16x8*)&lsA[(wr * WM + mi * 16 + fr) * BK + col];
      #pragma unroll
      for (int nj = 0; nj < FN; ++nj)
        bfv[nj] = *(const bf16x8*)&lsB[(wc * WN + nj * 16 + fr) * BK + col];
      #pragma unroll
      for (int mi = 0; mi < FM; ++mi)
        #pragma unroll
        for (int nj = 0; nj < FN; ++nj)
          acc[mi][nj] = __builtin_amdgcn_mfma_f32_16x16x32_bf16(af[mi], bfv[nj], acc[mi][nj], 0, 0, 0);
    }
  }

  const int r0 = (lane >> 4) * 4, c0 = lane & 15;
  #pragma unroll
  for (int mi = 0; mi < FM; ++mi) {
    #pragma unroll
    for (int nj = 0; nj < FN; ++nj) {
      const int c = n0 + wc * WN + nj * 16 + c0;
      const int rb = m0 + wr * WM + mi * 16 + r0;
      unsigned short us[4];
      #pragma unroll
      for (int j = 0; j < 4; ++j) {
        const int r = rb + j;
        float v = acc[mi][nj][j];
        if (RELU) v = fmaxf(v, 0.0f);
        if (RESID) v += Res[(size_t)r * ldc + c];
        const size_t o = (size_t)r * ldc + c;
        if (BF16OUT) { us[j] = f2b(v); ((unsigned short*)Cv)[o] = us[j]; }
        else ((float*)Cv)[o] = v;
      }
      if (WVT && c >= 1280) {
        // vT[(b*256 + c-1280)][t], t = rb&1023; 4 consecutive t -> one 8B store
        const int bb = rb >> 10, t0 = rb & 1023;
        bf16x4 pk;
        #pragma unroll
        for (int j = 0; j < 4; ++j) pk[j] = (short)us[j];
        *(bf16x4*)&vTo[((size_t)(bb * 256 + (c - 1280))) * 1024 + t0] = pk;
      }
    }
  }
}

extern "C" void kernel_launch(void* const* d_in, const int* in_sizes, int n_in,
                              void* d_out, int out_size, void* d_ws, size_t ws_size,
                              hipStream_t stream) {
  (void)in_sizes; (void)n_in; (void)out_size;
  const int*   idx      = (const int*)d_in[0];
  const float* tok_emb  = (const float*)d_in[1];
  const float* pos_emb  = (const float*)d_in[2];
  const float* q_proj   = (const float*)d_in[3];
  const float* kv_proj  = (const float*)d_in[4];
  const float* out_proj = (const float*)d_in[5];
  const float* fc_in    = (const float*)d_in[6];
  const float* fc_out   = (const float*)d_in[7];
  const float* scale    = (const float*)d_in[8];
  const float* out_scl  = (const float*)d_in[9];
  const float* lm_head  = (const float*)d_in[10];
  float* out = (float*)d_out;

  char* ws = (char*)d_ws;
  size_t off = 0;
  auto alloc = [&](size_t bytes) -> void* {
    void* p = ws + off;
    off += (bytes + 255) & ~(size_t)255;
    return p;
  };
  unsigned short* WqkvT = (unsigned short*)alloc((size_t)2560 * 1024 * 2);
  unsigned short* WoT   = WqkvT + (size_t)1536 * 1024;
  unsigned short* F1T   = (unsigned short*)alloc((size_t)4096 * 1024 * 2);
  unsigned short* F2T   = (unsigned short*)alloc((size_t)1024 * 4096 * 2);
  float*  xbuf  = (float*)alloc((size_t)2048 * 1024 * 4);
  float*  hbuf  = (float*)alloc((size_t)2048 * 1024 * 4);
  float*  h2buf = (float*)alloc((size_t)2048 * 1024 * 4);
  unsigned short* actb  = (unsigned short*)alloc((size_t)2048 * 1024 * 2);
  unsigned short* qkvb  = (unsigned short*)alloc((size_t)2048 * 1536 * 2);
  unsigned short* vT    = (unsigned short*)alloc((size_t)2 * 256 * 1024 * 2);
  unsigned short* LmT   = (unsigned short*)alloc((size_t)32000 * 1024 * 2);
  unsigned short* ob    = (unsigned short*)alloc((size_t)2048 * 1024 * 2);
  unsigned short* m1    = (unsigned short*)alloc((size_t)2048 * 4096 * 2);
  if (off > ws_size) return;

  const dim3 thr(256);

  embed_kernel<<<dim3(2048), thr, 0, stream>>>(idx, tok_emb, pos_emb, xbuf);

  for (int l = 0; l < 8; ++l) {
    const float* qp  = q_proj + (size_t)l * 1024 * 1024;
    const float* op  = out_proj + (size_t)l * 1024 * 1024;
    const float* kvp = kv_proj + (size_t)l * 2 * 1024 * 256;
    // all weight transposes in one launch
    transpose_all<<<dim3(10752), thr, 0, stream>>>(
        qp, op, kvp, WqkvT,
        fc_in + (size_t)l * 1024 * 4096, fc_out + (size_t)l * 4096 * 1024, F1T, F2T);

    const float* w1 = scale + (size_t)l * 2048;
    const float* w2 = w1 + 1024;

    ln_kernel<true><<<dim3(2048), thr, 0, stream>>>(xbuf, w1, hbuf, actb);
    // qkv = h @ Wqkv (V columns also written transposed into vT)
    gemm_nt<128, 64, true, false, false, true><<<dim3(16, 24), thr, 0, stream>>>(
        actb, WqkvT, qkvb, nullptr, vT, 1024, 1024, 1024, 1536);
    attn_fused<<<dim3(16, 32), thr, 0, stream>>>(qkvb, vT, ob);
    gemm_nt<128, 64, false, false, true><<<dim3(16, 16), thr, 0, stream>>>(
        ob, WoT, xbuf, hbuf, nullptr, 1024, 1024, 1024, 1024);
    ln_kernel<true><<<dim3(2048), thr, 0, stream>>>(xbuf, w2, h2buf, actb);
    gemm_nt<128, 128, true, true, false><<<dim3(16, 32), thr, 0, stream>>>(
        actb, F1T, m1, nullptr, nullptr, 1024, 1024, 1024, 4096);
    gemm_nt<128, 64, false, false, true><<<dim3(16, 16), thr, 0, stream>>>(
        m1, F2T, xbuf, h2buf, nullptr, 4096, 4096, 4096, 1024);
  }

  transpose_w<<<dim3(1000, 32), thr, 0, stream>>>(lm_head, LmT, 32000, 0, 1024);
  ln_kernel<false><<<dim3(2048), thr, 0, stream>>>(xbuf, out_scl, nullptr, actb);
  gemm_nt<128, 128, false, false, false><<<dim3(16, 250), thr, 0, stream>>>(
      actb, LmT, out, nullptr, nullptr, 1024, 1024, 1024, 32000);
}

// Round 14
// 1536.306 us; speedup vs baseline: 1.2016x; 1.0468x over previous
//
#include <hip/hip_runtime.h>
#include <hip/hip_bf16.h>

typedef __attribute__((ext_vector_type(8))) short bf16x8;
typedef __attribute__((ext_vector_type(4))) short bf16x4;
typedef __attribute__((ext_vector_type(4))) float f32x4;

#define LB __launch_bounds__(256)

__device__ __forceinline__ unsigned short f2b(float f) {
  __hip_bfloat16 h = __float2bfloat16(f);
  return __builtin_bit_cast(unsigned short, h);
}

// async global->LDS, 16B per lane. LDS dest must be wave-uniform base + lane*16.
#define GLDS(gp, lp)                                                        \
  __builtin_amdgcn_global_load_lds(                                         \
      (const __attribute__((address_space(1))) void*)(gp),                  \
      (__attribute__((address_space(3))) void*)(lp), 16, 0, 0)

// ---------------- embed ----------------
__global__ LB void embed_kernel(const int* __restrict__ idx, const float* __restrict__ tok,
                                const float* __restrict__ pos, float* __restrict__ X) {
  const int m = blockIdx.x;
  const int t = m & 1023;
  const int token = idx[m];
  const int c = threadIdx.x * 4;
  const float4 a = *(const float4*)(tok + (size_t)token * 1024 + c);
  const float4 p = *(const float4*)(pos + (size_t)t * 1024 + c);
  float4 o; o.x = a.x + p.x; o.y = a.y + p.y; o.z = a.z + p.z; o.w = a.w + p.w;
  *(float4*)(X + (size_t)m * 1024 + c) = o;
}

// ---------------- layernorm ----------------
template<bool WF32>
__global__ LB void ln_kernel(const float* __restrict__ X, const float* __restrict__ W,
                             float* __restrict__ Yf, unsigned short* __restrict__ Yb) {
  const int row = blockIdx.x;
  const float* xr = X + (size_t)row * 1024;
  const int c = threadIdx.x * 4;
  const float4 v = *(const float4*)(xr + c);
  float s = v.x + v.y + v.z + v.w;
  float q = v.x*v.x + v.y*v.y + v.z*v.z + v.w*v.w;
  #pragma unroll
  for (int d = 32; d > 0; d >>= 1) { s += __shfl_down(s, d); q += __shfl_down(q, d); }
  __shared__ float ss[4], sq[4];
  const int wid = threadIdx.x >> 6;
  if ((threadIdx.x & 63) == 0) { ss[wid] = s; sq[wid] = q; }
  __syncthreads();
  const float fs = ss[0] + ss[1] + ss[2] + ss[3];
  const float fq = sq[0] + sq[1] + sq[2] + sq[3];
  const float mean = fs * (1.0f / 1024.0f);
  const float var = fq * (1.0f / 1024.0f) - mean * mean;
  const float rstd = rsqrtf(var + 1e-5f);
  const float4 w = *(const float4*)(W + c);
  float4 o;
  o.x = (v.x - mean) * rstd * w.x; o.y = (v.y - mean) * rstd * w.y;
  o.z = (v.z - mean) * rstd * w.z; o.w = (v.w - mean) * rstd * w.w;
  if (WF32) *(float4*)(Yf + (size_t)row * 1024 + c) = o;
  unsigned long long pk = (unsigned long long)f2b(o.x)
      | ((unsigned long long)f2b(o.y) << 16)
      | ((unsigned long long)f2b(o.z) << 32)
      | ((unsigned long long)f2b(o.w) << 48);
  *(unsigned long long*)(Yb + (size_t)row * 1024 + c) = pk;
}

// ---------------- transpose tile body: dst[rowOff+c][r] = bf16(src[r][c]) ----------------
__device__ __forceinline__ void tr_body(const float* __restrict__ src,
                                        unsigned short* __restrict__ dst,
                                        int C, int rowOff, int ldDst, int bx, int by) {
  __shared__ float tile[32][33];
  const int c0 = bx * 32, r0 = by * 32;
  const int tx = threadIdx.x & 31, ty = threadIdx.x >> 5;
  #pragma unroll
  for (int u = 0; u < 4; ++u)
    tile[ty + u * 8][tx] = src[(size_t)(r0 + ty + u * 8) * C + c0 + tx];
  __syncthreads();
  const int ci = threadIdx.x >> 4;
  const int rp = threadIdx.x & 15;
  #pragma unroll
  for (int u = 0; u < 2; ++u) {
    const int c = ci + u * 16;
    unsigned int pk = (unsigned int)f2b(tile[rp * 2][c])
                    | ((unsigned int)f2b(tile[rp * 2 + 1][c]) << 16);
    *(unsigned int*)&dst[(size_t)(rowOff + c0 + c) * ldDst + r0 + rp * 2] = pk;
  }
}

// lm_head transpose (standalone)
__global__ LB void transpose_w(const float* __restrict__ src, unsigned short* __restrict__ dst,
                               int C, int rowOff, int ldDst) {
  tr_body(src, dst, C, rowOff, ldDst, blockIdx.x, blockIdx.y);
}

// all per-layer weight transposes in ONE launch: 10752 flat blocks
__global__ LB void transpose_all(const float* __restrict__ qp, const float* __restrict__ op,
                                 const float* __restrict__ kvp, unsigned short* __restrict__ dstQ,
                                 const float* __restrict__ f1, const float* __restrict__ f2,
                                 unsigned short* __restrict__ F1T, unsigned short* __restrict__ F2T) {
  int id = blockIdx.x;
  if (id < 2560) {
    const float* src; int C, rowOff, bx, by;
    if (id < 2048) {
      src = (id < 1024) ? qp : op;
      rowOff = (id < 1024) ? 0 : 1536;
      id &= 1023; C = 1024; bx = id & 31; by = id >> 5;
    } else {
      id -= 2048;
      src = (id < 256) ? kvp : (kvp + 1024 * 256);
      rowOff = (id < 256) ? 1024 : 1280;
      id &= 255; C = 256; bx = id & 7; by = id >> 3;
    }
    tr_body(src, dstQ, C, rowOff, 1024, bx, by);
  } else {
    id -= 2560;
    if (id < 4096) {
      tr_body(f1, F1T, 4096, 0, 1024, id & 127, id >> 7);
    } else {
      id -= 4096;
      tr_body(f2, F2T, 1024, 0, 4096, id & 31, id >> 5);
    }
  }
}

// ---------------- fused flash attention: dbuf K/V, 64-row q-tiles, 2 blocks/CU ----------------
__global__ LB void attn_fused(const unsigned short* __restrict__ qkvb,
                              const unsigned short* __restrict__ vT,
                              unsigned short* __restrict__ ob) {
  const int qt = 15 - blockIdx.x, bh = blockIdx.y;
  const int b = bh >> 4, hh = bh & 15, n = hh & 3;
  const int tid = threadIdx.x, lane = tid & 63, w = tid >> 6;
  const int g = lane >> 4, c = lane & 15;
  const int q0w = qt * 64 + w * 16;
  const int qrow = q0w + c;

  __shared__ unsigned short lsK[2][64 * 64];
  __shared__ unsigned short lsV[2][64 * 64];
  __shared__ unsigned short lsP[4][16 * 64];
  unsigned short* Pw = lsP[w];

  bf16x8 qf[2];
  {
    const unsigned short* Qb = qkvb + (size_t)(b * 1024 + q0w) * 1536 + hh * 64;
    #pragma unroll
    for (int ks = 0; ks < 2; ++ks)
      qf[ks] = *(const bf16x8*)(Qb + (size_t)c * 1536 + ks * 32 + g * 8);
  }

  f32x4 accO[4] = {};
  float mr = -1e30f, lr = 0.0f;

  const int srow = tid >> 3;
  const int scol = ((tid & 7) ^ (srow & 7)) << 3;
  const unsigned short* gK = qkvb + (size_t)(b * 1024 + srow) * 1536 + 1024 + n * 64 + scol;
  const unsigned short* gV = vT + (size_t)((b * 4 + n) * 64 + srow) * 1024 + scol;

  GLDS(gK, &lsK[0][tid * 8]);
  GLDS(gK + (size_t)32 * 1536, &lsK[0][tid * 8 + 2048]);
  GLDS(gV, &lsV[0][tid * 8]);
  GLDS(gV + (size_t)32 * 1024, &lsV[0][tid * 8 + 2048]);
  __syncthreads();

  for (int kt = 0; kt <= qt; ++kt) {
    const int cur = kt & 1;
    if (kt < qt) {
      const size_t ko = (size_t)(kt + 1) * 64;
      GLDS(gK + ko * 1536, &lsK[cur ^ 1][tid * 8]);
      GLDS(gK + (ko + 32) * 1536, &lsK[cur ^ 1][tid * 8 + 2048]);
      GLDS(gV + ko, &lsV[cur ^ 1][tid * 8]);
      GLDS(gV + ko + (size_t)32 * 1024, &lsV[cur ^ 1][tid * 8 + 2048]);
    }
    const unsigned short* K_ = lsK[cur];
    const unsigned short* V_ = lsV[cur];
    const bool dg = (kt == qt);
    const int kb = kt * 64;

    f32x4 st[4] = {};
    #pragma unroll
    for (int ks = 0; ks < 2; ++ks) {
      const int col = (((ks * 4 + g) ^ (lane & 7)) << 3);
      bf16x8 kf[4];
      #pragma unroll
      for (int mi = 0; mi < 4; ++mi)
        kf[mi] = *(const bf16x8*)&K_[(mi * 16 + c) * 64 + col];
      #pragma unroll
      for (int mi = 0; mi < 4; ++mi)
        st[mi] = __builtin_amdgcn_mfma_f32_16x16x32_bf16(kf[mi], qf[ks], st[mi], 0, 0, 0);
    }

    float mx = mr;
    #pragma unroll
    for (int mi = 0; mi < 4; ++mi)
      #pragma unroll
      for (int j = 0; j < 4; ++j) {
        float v = st[mi][j] * 0.125f;
        if (dg && (kb + mi * 16 + g * 4 + j) > qrow) v = -1e30f;
        st[mi][j] = v;
        mx = fmaxf(mx, v);
      }
    mx = fmaxf(mx, __shfl_xor(mx, 16));
    mx = fmaxf(mx, __shfl_xor(mx, 32));
    const float al = __expf(mr - mx);
    float sum = 0.0f;
    #pragma unroll
    for (int mi = 0; mi < 4; ++mi) {
      bf16x4 pk;
      #pragma unroll
      for (int j = 0; j < 4; ++j) {
        const float e = __expf(st[mi][j] - mx);
        sum += e;
        pk[j] = (short)f2b(e);
      }
      *(bf16x4*)&Pw[c * 64 + ((mi * 16 + g * 4) ^ ((c & 7) << 3))] = pk;
    }
    sum += __shfl_xor(sum, 16);
    sum += __shfl_xor(sum, 32);
    lr = lr * al + sum;
    mr = mx;

    float aj[4];
    #pragma unroll
    for (int j = 0; j < 4; ++j) aj[j] = __shfl(al, g * 4 + j);
    #pragma unroll
    for (int dj = 0; dj < 4; ++dj)
      #pragma unroll
      for (int j = 0; j < 4; ++j) accO[dj][j] *= aj[j];

    #pragma unroll
    for (int ks = 0; ks < 2; ++ks) {
      const int col = (((ks * 4 + g) ^ (c & 7)) << 3);
      const bf16x8 pa = *(const bf16x8*)&Pw[c * 64 + col];
      bf16x8 vf[4];
      #pragma unroll
      for (int dj = 0; dj < 4; ++dj)
        vf[dj] = *(const bf16x8*)&V_[(dj * 16 + c) * 64 + col];
      #pragma unroll
      for (int dj = 0; dj < 4; ++dj)
        accO[dj] = __builtin_amdgcn_mfma_f32_16x16x32_bf16(pa, vf[dj], accO[dj], 0, 0, 0);
    }
    __syncthreads();
  }

  const float linv = 1.0f / lr;
  float lj[4];
  #pragma unroll
  for (int j = 0; j < 4; ++j) lj[j] = __shfl(linv, g * 4 + j);
  unsigned short* obase = ob + (size_t)(b * 1024 + q0w) * 1024 + hh * 64;
  #pragma unroll
  for (int dj = 0; dj < 4; ++dj)
    #pragma unroll
    for (int j = 0; j < 4; ++j)
      obase[(size_t)(g * 4 + j) * 1024 + dj * 16 + c] = f2b(accO[dj][j] * lj[j]);
}

// ---------------- NT GEMM: C = A[M,K]*Bt[N,K]^T, bf16 in, f32 acc ----------------
// BK=64, XOR chunk swizzle; bx=M-tile fastest + XCD chunk swizzle.
// DBUF: double-buffered LDS, prefetch-next-before-compute, ONE barrier per K-step
// (drain lands after compute) — for low-block-count launches (1-2 blocks/CU).
// WVT: for output cols >=1280 (V part of qkv) also write vT[b][c-1280][t] packed.
template<int BM, int BN, bool BF16OUT, bool RELU, bool RESID, bool WVT = false, bool DBUF = false>
__global__ LB void gemm_nt(const unsigned short* __restrict__ A, const unsigned short* __restrict__ Bt,
                           void* __restrict__ Cv, const float* __restrict__ Res,
                           unsigned short* __restrict__ vTo,
                           int K, int lda, int ldb, int ldc) {
  constexpr int BK = 64;
  constexpr int WM = BM / 2, WN = BN / 2;
  constexpr int FM = WM / 16, FN = WN / 16;
  constexpr int PA = BM / 32, PB = BN / 32;
  constexpr int NB = DBUF ? 2 : 1;
  int f = blockIdx.x + gridDim.x * blockIdx.y;
  const int nwg = gridDim.x * gridDim.y;
  if ((nwg & 7) == 0) f = (f & 7) * (nwg >> 3) + (f >> 3);
  const int bx = f % gridDim.x, by = f / gridDim.x;

  const int tid = threadIdx.x;
  const int lane = tid & 63, wid = tid >> 6;
  const int wr = wid >> 1, wc = wid & 1;
  const int m0 = bx * BM, n0 = by * BN;

  __shared__ unsigned short lsA[NB][BM * BK];
  __shared__ unsigned short lsB[NB][BN * BK];

  f32x4 acc[FM][FN] = {};

  const int srow = tid >> 3;
  const int scol = ((tid & 7) ^ (srow & 7)) << 3;
  const unsigned short* gA = A + (size_t)(m0 + srow) * lda + scol;
  const unsigned short* gB = Bt + (size_t)(n0 + srow) * ldb + scol;

  const int fr = lane & 15;
  const int j7 = lane & 7;
  const int g4 = lane >> 4;

  if (DBUF) {
    // prologue: stage k=0 into buffer 0
    #pragma unroll
    for (int p = 0; p < PA; ++p) GLDS(gA + (size_t)(p * 32) * lda, &lsA[0][tid * 8 + p * 2048]);
    #pragma unroll
    for (int p = 0; p < PB; ++p) GLDS(gB + (size_t)(p * 32) * ldb, &lsB[0][tid * 8 + p * 2048]);
    __syncthreads();
  }

  for (int k0 = 0; k0 < K; k0 += BK) {
    int cur = 0;
    if (DBUF) {
      cur = (k0 >> 6) & 1;
      if (k0 + BK < K) {   // prefetch next tile into other buffer (no wait)
        #pragma unroll
        for (int p = 0; p < PA; ++p)
          GLDS(gA + (size_t)(p * 32) * lda + k0 + BK, &lsA[cur ^ 1][tid * 8 + p * 2048]);
        #pragma unroll
        for (int p = 0; p < PB; ++p)
          GLDS(gB + (size_t)(p * 32) * ldb + k0 + BK, &lsB[cur ^ 1][tid * 8 + p * 2048]);
      }
    } else {
      if (k0) __syncthreads();
      #pragma unroll
      for (int p = 0; p < PA; ++p)
        GLDS(gA + (size_t)(p * 32) * lda + k0, &lsA[0][tid * 8 + p * 2048]);
      #pragma unroll
      for (int p = 0; p < PB; ++p)
        GLDS(gB + (size_t)(p * 32) * ldb + k0, &lsB[0][tid * 8 + p * 2048]);
      __syncthreads();
    }

    const unsigned short* LA = lsA[cur];
    const unsigned short* LBp = lsB[cur];
    #pragma unroll
    for (int ks = 0; ks < 2; ++ks) {
      const int col = (((ks * 4 + g4) ^ j7) << 3);
      bf16x8 af[FM], bfv[FN];
      #pragma unroll
      for (int mi = 0; mi < FM; ++mi)
        af[mi] = *(const bf16x8*)&LA[(wr * WM + mi * 16 + fr) * BK + col];
      #pragma unroll
      for (int nj = 0; nj < FN; ++nj)
        bfv[nj] = *(const bf16x8*)&LBp[(wc * WN + nj * 16 + fr) * BK + col];
      #pragma unroll
      for (int mi = 0; mi < FM; ++mi)
        #pragma unroll
        for (int nj = 0; nj < FN; ++nj)
          acc[mi][nj] = __builtin_amdgcn_mfma_f32_16x16x32_bf16(af[mi], bfv[nj], acc[mi][nj], 0, 0, 0);
    }
    if (DBUF) __syncthreads();   // drains prefetch; all waves done reading cur
  }

  const int r0 = (lane >> 4) * 4, c0 = lane & 15;
  #pragma unroll
  for (int mi = 0; mi < FM; ++mi) {
    #pragma unroll
    for (int nj = 0; nj < FN; ++nj) {
      const int c = n0 + wc * WN + nj * 16 + c0;
      const int rb = m0 + wr * WM + mi * 16 + r0;
      unsigned short us[4];
      #pragma unroll
      for (int j = 0; j < 4; ++j) {
        const int r = rb + j;
        float v = acc[mi][nj][j];
        if (RELU) v = fmaxf(v, 0.0f);
        if (RESID) v += Res[(size_t)r * ldc + c];
        const size_t o = (size_t)r * ldc + c;
        if (BF16OUT) { us[j] = f2b(v); ((unsigned short*)Cv)[o] = us[j]; }
        else ((float*)Cv)[o] = v;
      }
      if (WVT && c >= 1280) {
        const int bb = rb >> 10, t0 = rb & 1023;
        bf16x4 pk;
        #pragma unroll
        for (int j = 0; j < 4; ++j) pk[j] = (short)us[j];
        *(bf16x4*)&vTo[((size_t)(bb * 256 + (c - 1280))) * 1024 + t0] = pk;
      }
    }
  }
}

extern "C" void kernel_launch(void* const* d_in, const int* in_sizes, int n_in,
                              void* d_out, int out_size, void* d_ws, size_t ws_size,
                              hipStream_t stream) {
  (void)in_sizes; (void)n_in; (void)out_size;
  const int*   idx      = (const int*)d_in[0];
  const float* tok_emb  = (const float*)d_in[1];
  const float* pos_emb  = (const float*)d_in[2];
  const float* q_proj   = (const float*)d_in[3];
  const float* kv_proj  = (const float*)d_in[4];
  const float* out_proj = (const float*)d_in[5];
  const float* fc_in    = (const float*)d_in[6];
  const float* fc_out   = (const float*)d_in[7];
  const float* scale    = (const float*)d_in[8];
  const float* out_scl  = (const float*)d_in[9];
  const float* lm_head  = (const float*)d_in[10];
  float* out = (float*)d_out;

  char* ws = (char*)d_ws;
  size_t off = 0;
  auto alloc = [&](size_t bytes) -> void* {
    void* p = ws + off;
    off += (bytes + 255) & ~(size_t)255;
    return p;
  };
  unsigned short* WqkvT = (unsigned short*)alloc((size_t)2560 * 1024 * 2);
  unsigned short* WoT   = WqkvT + (size_t)1536 * 1024;
  unsigned short* F1T   = (unsigned short*)alloc((size_t)4096 * 1024 * 2);
  unsigned short* F2T   = (unsigned short*)alloc((size_t)1024 * 4096 * 2);
  float*  xbuf  = (float*)alloc((size_t)2048 * 1024 * 4);
  float*  hbuf  = (float*)alloc((size_t)2048 * 1024 * 4);
  float*  h2buf = (float*)alloc((size_t)2048 * 1024 * 4);
  unsigned short* actb  = (unsigned short*)alloc((size_t)2048 * 1024 * 2);
  unsigned short* qkvb  = (unsigned short*)alloc((size_t)2048 * 1536 * 2);
  unsigned short* vT    = (unsigned short*)alloc((size_t)2 * 256 * 1024 * 2);
  unsigned short* LmT   = (unsigned short*)alloc((size_t)32000 * 1024 * 2);
  unsigned short* ob    = (unsigned short*)alloc((size_t)2048 * 1024 * 2);
  unsigned short* m1    = (unsigned short*)alloc((size_t)2048 * 4096 * 2);
  if (off > ws_size) return;

  const dim3 thr(256);

  embed_kernel<<<dim3(2048), thr, 0, stream>>>(idx, tok_emb, pos_emb, xbuf);

  for (int l = 0; l < 8; ++l) {
    const float* qp  = q_proj + (size_t)l * 1024 * 1024;
    const float* op  = out_proj + (size_t)l * 1024 * 1024;
    const float* kvp = kv_proj + (size_t)l * 2 * 1024 * 256;
    transpose_all<<<dim3(10752), thr, 0, stream>>>(
        qp, op, kvp, WqkvT,
        fc_in + (size_t)l * 1024 * 4096, fc_out + (size_t)l * 4096 * 1024, F1T, F2T);

    const float* w1 = scale + (size_t)l * 2048;
    const float* w2 = w1 + 1024;

    ln_kernel<true><<<dim3(2048), thr, 0, stream>>>(xbuf, w1, hbuf, actb);
    // qkv = h @ Wqkv (V columns also written transposed into vT), dbuf
    gemm_nt<128, 64, true, false, false, true, true><<<dim3(16, 24), thr, 0, stream>>>(
        actb, WqkvT, qkvb, nullptr, vT, 1024, 1024, 1024, 1536);
    attn_fused<<<dim3(16, 32), thr, 0, stream>>>(qkvb, vT, ob);
    // x = h + o @ Wo, dbuf
    gemm_nt<128, 64, false, false, true, false, true><<<dim3(16, 16), thr, 0, stream>>>(
        ob, WoT, xbuf, hbuf, nullptr, 1024, 1024, 1024, 1024);
    ln_kernel<true><<<dim3(2048), thr, 0, stream>>>(xbuf, w2, h2buf, actb);
    // m1 = relu(h2 @ fc1), dbuf
    gemm_nt<128, 128, true, true, false, false, true><<<dim3(16, 32), thr, 0, stream>>>(
        actb, F1T, m1, nullptr, nullptr, 1024, 1024, 1024, 4096);
    // x = h2 + m1 @ fc2, dbuf
    gemm_nt<128, 64, false, false, true, false, true><<<dim3(16, 16), thr, 0, stream>>>(
        m1, F2T, xbuf, h2buf, nullptr, 4096, 4096, 4096, 1024);
  }

  transpose_w<<<dim3(1000, 32), thr, 0, stream>>>(lm_head, LmT, 32000, 0, 1024);
  ln_kernel<false><<<dim3(2048), thr, 0, stream>>>(xbuf, out_scl, nullptr, actb);
  // logits: single-buffer path (high block residency already overlaps drains)
  gemm_nt<128, 128, false, false, false><<<dim3(16, 250), thr, 0, stream>>>(
      actb, LmT, out, nullptr, nullptr, 1024, 1024, 1024, 32000);
}